// Round 1
// baseline (372.440 us; speedup 1.0000x reference)
//
#include <hip/hip_runtime.h>
#include <cstdint>

#define L_SEQ   1024
#define DMODEL  768
#define DINNER  1536
#define NHEADS  24
#define HEADDIM 64
#define DSTATE  192
#define NPAIR   48
#define DPROJ   3480
#define NCHUNK  16
#define QCH     64
#define EPSF    1e-6f

// ---------- helpers ----------
__device__ __forceinline__ float blockReduceSum256(float v, float* red) {
#pragma unroll
  for (int m = 32; m; m >>= 1) v += __shfl_xor(v, m, 64);
  int wid = threadIdx.x >> 6, lane = threadIdx.x & 63;
  if (lane == 0) red[wid] = v;
  __syncthreads();
  float s = red[0] + red[1] + red[2] + red[3];
  __syncthreads();
  return s;
}

// ---------- K1: pre RMSNorm ----------
__global__ __launch_bounds__(256) void k_prenorm(const float* __restrict__ x,
                                                 const float* __restrict__ pre_scale,
                                                 float* __restrict__ h) {
  __shared__ float red[4];
  int l = blockIdx.x, tid = threadIdx.x;
  const float* xr = x + (size_t)l * DMODEL;
  float v[3]; float ss = 0.f;
#pragma unroll
  for (int k = 0; k < 3; ++k) { v[k] = xr[tid + k * 256]; ss += v[k] * v[k]; }
  ss = blockReduceSum256(ss, red);
  float r = rsqrtf(ss * (1.f / DMODEL) + EPSF);
#pragma unroll
  for (int k = 0; k < 3; ++k) {
    int i = tid + k * 256;
    h[(size_t)l * DMODEL + i] = v[k] * r * (1.f + pre_scale[i]);
  }
}

// ---------- K2/K9: fp32 SGEMM, 64x64 tile, BK=16, 4x4 per thread ----------
__global__ __launch_bounds__(256) void k_sgemm64(const float* __restrict__ A,
                                                 const float* __restrict__ B,
                                                 float* __restrict__ C,
                                                 int M, int N, int K) {
  __shared__ float As[16][68];
  __shared__ float Bs[16][68];
  const int tid = threadIdx.x;
  const int bm = blockIdx.y * 64, bn = blockIdx.x * 64;
  const int tx = tid & 15, ty = tid >> 4;
  const int ar = tid >> 2, akq = (tid & 3) << 2;
  const int bk = tid >> 4, bnq = (tid & 15) << 2;
  float acc[4][4] = {};
  for (int k0 = 0; k0 < K; k0 += 16) {
    float4 av = *(const float4*)(A + (size_t)(bm + ar) * K + k0 + akq);
    As[akq + 0][ar] = av.x; As[akq + 1][ar] = av.y;
    As[akq + 2][ar] = av.z; As[akq + 3][ar] = av.w;
    int col = bn + bnq;
    float4 bv = make_float4(0.f, 0.f, 0.f, 0.f);
    if (col + 3 < N) {
      bv = *(const float4*)(B + (size_t)(k0 + bk) * N + col);
    } else {
      const float* bp = B + (size_t)(k0 + bk) * N;
      if (col     < N) bv.x = bp[col];
      if (col + 1 < N) bv.y = bp[col + 1];
      if (col + 2 < N) bv.z = bp[col + 2];
    }
    *(float4*)&Bs[bk][bnq] = bv;
    __syncthreads();
#pragma unroll
    for (int kk = 0; kk < 16; ++kk) {
      const float4 a4 = *(const float4*)&As[kk][ty << 2];
      const float4 b4 = *(const float4*)&Bs[kk][tx << 2];
      float avv[4] = {a4.x, a4.y, a4.z, a4.w};
      float bvv[4] = {b4.x, b4.y, b4.z, b4.w};
#pragma unroll
      for (int i = 0; i < 4; ++i)
#pragma unroll
        for (int j = 0; j < 4; ++j) acc[i][j] = fmaf(avv[i], bvv[j], acc[i][j]);
    }
    __syncthreads();
  }
#pragma unroll
  for (int i = 0; i < 4; ++i) {
    int row = bm + (ty << 2) + i;
    int col = bn + (tx << 2);
    if (col + 3 < N) {
      *(float4*)(C + (size_t)row * N + col) =
          make_float4(acc[i][0], acc[i][1], acc[i][2], acc[i][3]);
    } else {
#pragma unroll
      for (int j = 0; j < 4; ++j)
        if (col + j < N) C[(size_t)row * N + col + j] = acc[i][j];
    }
  }
}

// ---------- K3: dt softplus + inclusive cumsum (one block per head) ----------
__global__ __launch_bounds__(1024) void k_dtscan(const float* __restrict__ zx,
                                                 const float* __restrict__ dt_bias,
                                                 const float* __restrict__ A_log,
                                                 float* __restrict__ halfdt,
                                                 float* __restrict__ cfac,
                                                 float* __restrict__ cumdt,
                                                 float* __restrict__ cumD) {
  __shared__ float sdt[L_SEQ];
  __shared__ float sbuf[L_SEQ];
  int hh = blockIdx.x, l = threadIdx.x;
  float draw = zx[(size_t)l * DPROJ + 3456 + hh] + dt_bias[hh];
  float dt = (draw > 20.f) ? draw : log1pf(expf(draw));
  float Ah = -(expf(A_log[hh]) + 1e-4f);
  sdt[l] = dt;
  sbuf[l] = dt;
  __syncthreads();
  for (int off = 1; off < L_SEQ; off <<= 1) {
    float a = sbuf[l];
    float b = (l >= off) ? sbuf[l - off] : 0.f;
    __syncthreads();
    sbuf[l] = a + b;
    __syncthreads();
  }
  float cd = sbuf[l];
  float dnext = (l < L_SEQ - 1) ? sdt[l + 1] : 0.f;
  size_t idx = (size_t)hh * L_SEQ + l;
  halfdt[idx] = 0.5f * dt;
  cfac[idx]   = 0.5f * (dt + dnext);
  cumdt[idx]  = cd;
  cumD[idx]   = Ah * cd;   // cumsum(dt*A) == A*cumsum(dt), A is per-head const
}

// ---------- K4: rotate B/C per head + gather U contiguous ----------
__global__ __launch_bounds__(256) void k_rotate(const float* __restrict__ zx,
                                                const float* __restrict__ cumdt,
                                                const float* __restrict__ omega,
                                                float* __restrict__ Brot,
                                                float* __restrict__ Crot,
                                                float* __restrict__ U) {
  int l = blockIdx.x, tid = threadIdx.x;
  const float* row = zx + (size_t)l * DPROJ;
  // U copy: u[l][h][p] = zx[l][1536 + h*64 + p] -> U[(h*L+l)*64 + p]
  for (int i = tid; i < 384; i += 256) {
    float4 v = *(const float4*)(row + 1536 + i * 4);
    int hh = i >> 4;             // (i*4)/64
    int p = (i & 15) << 2;       // (i*4)%64
    *(float4*)&U[((size_t)(hh * L_SEQ + l)) * HEADDIM + p] = v;
  }
  // rotation: tasks (h, j) j in [0,96): pair n=2j,2j+1
  for (int i = tid; i < NHEADS * 96; i += 256) {
    int hh = i / 96, j = i - hh * 96;
    int n = 2 * j;
    float b0 = row[3072 + n], b1 = row[3072 + n + 1];
    float c0 = row[3264 + n], c1 = row[3264 + n + 1];
    size_t base = ((size_t)(hh * L_SEQ + l)) * DSTATE + n;
    if (j < NPAIR) {
      float ph = cumdt[hh * L_SEQ + l] * omega[hh * NPAIR + j];
      float sp, cp;
      sincosf(ph, &sp, &cp);
      Brot[base]     =  b0 * cp + b1 * sp;   // rotate by -phi
      Brot[base + 1] = -b0 * sp + b1 * cp;
      Crot[base]     =  c0 * cp - c1 * sp;   // rotate by +phi
      Crot[base + 1] =  c0 * sp + c1 * cp;
    } else {
      Brot[base] = b0; Brot[base + 1] = b1;
      Crot[base] = c0; Crot[base + 1] = c1;
    }
  }
}

// ---------- K5: per-(head,chunk) state contribution X_c[p][n] ----------
__global__ __launch_bounds__(256) void k_chunkX(const float* __restrict__ Brot,
                                                const float* __restrict__ U,
                                                const float* __restrict__ cumD,
                                                const float* __restrict__ cfac,
                                                float* __restrict__ X) {
  const int c = blockIdx.x, hh = blockIdx.y;
  const int tid = threadIdx.x;
  const size_t hl = (size_t)hh * L_SEQ;
  const int l0 = c * QCH;
  __shared__ float Bs[QCH][DSTATE];  // 48 KB
  __shared__ float su[QCH][HEADDIM]; // 16 KB
  for (int i = tid; i < QCH * 48; i += 256) {
    int m = i / 48, q = i - m * 48;
    *(float4*)&Bs[m][q << 2] = *(const float4*)&Brot[(hl + l0 + m) * DSTATE + (q << 2)];
  }
  float dlast = cumD[hl + l0 + QCH - 1];
  for (int i = tid; i < QCH * 16; i += 256) {
    int m = i >> 4, q = i & 15;
    float s = expf(dlast - cumD[hl + l0 + m]) * cfac[hl + l0 + m];
    float4 v = *(const float4*)&U[(hl + l0 + m) * HEADDIM + (q << 2)];
    v.x *= s; v.y *= s; v.z *= s; v.w *= s;
    *(float4*)&su[m][q << 2] = v;
  }
  __syncthreads();
  const int ngrp = tid & 15, pgrp = tid >> 4;
  const int n0 = ngrp * 12, p0 = pgrp << 2;
  float acc[12][4] = {};
  for (int m = 0; m < QCH; ++m) {
    const float4 uv = *(const float4*)&su[m][p0];
    const float4 b0 = *(const float4*)&Bs[m][n0];
    const float4 b1 = *(const float4*)&Bs[m][n0 + 4];
    const float4 b2 = *(const float4*)&Bs[m][n0 + 8];
    float u4[4] = {uv.x, uv.y, uv.z, uv.w};
    float bb[12] = {b0.x, b0.y, b0.z, b0.w, b1.x, b1.y, b1.z, b1.w, b2.x, b2.y, b2.z, b2.w};
#pragma unroll
    for (int j = 0; j < 12; ++j)
#pragma unroll
      for (int i = 0; i < 4; ++i) acc[j][i] = fmaf(bb[j], u4[i], acc[j][i]);
  }
  const size_t obase = ((size_t)(hh * NCHUNK + c)) * (HEADDIM * DSTATE);
#pragma unroll
  for (int i = 0; i < 4; ++i)
#pragma unroll
    for (int j4 = 0; j4 < 3; ++j4)
      *(float4*)&X[obase + (size_t)(p0 + i) * DSTATE + n0 + j4 * 4] =
          make_float4(acc[j4 * 4 + 0][i], acc[j4 * 4 + 1][i], acc[j4 * 4 + 2][i], acc[j4 * 4 + 3][i]);
}

// ---------- K6: sequential chunk-state pass (parallel over elements) ----------
__global__ __launch_bounds__(256) void k_statepass(const float* __restrict__ X,
                                                   const float* __restrict__ cumD,
                                                   float* __restrict__ Hs) {
  int hh = blockIdx.x >> 3, part = blockIdx.x & 7;
  int tid = threadIdx.x;
  const size_t hl = (size_t)hh * L_SEQ;
  float Hc[6] = {0.f, 0.f, 0.f, 0.f, 0.f, 0.f};
  for (int c = 0; c < NCHUNK; ++c) {
    float r = 1.f;
    if (c > 0) r = expf(cumD[hl + c * QCH + QCH - 1] - cumD[hl + c * QCH - 1]);
    size_t base = ((size_t)(hh * NCHUNK + c)) * (HEADDIM * DSTATE) + part * 1536 + tid;
#pragma unroll
    for (int k = 0; k < 6; ++k) {
      Hs[base + k * 256] = Hc[k];
      Hc[k] = fmaf(r, Hc[k], X[base + k * 256]);
    }
  }
}

// ---------- K7: per-(head,chunk) output Y ----------
__global__ __launch_bounds__(256) void k_yout(const float* __restrict__ Brot,
                                              const float* __restrict__ Crot,
                                              const float* __restrict__ U,
                                              const float* __restrict__ Hs,
                                              const float* __restrict__ cumD,
                                              const float* __restrict__ cfac,
                                              const float* __restrict__ halfdt,
                                              const float* __restrict__ Dvec,
                                              float* __restrict__ Yout) {
  const int c = blockIdx.x, hh = blockIdx.y;
  const int tid = threadIdx.x;
  const int tx = tid & 15, ty = tid >> 4;
  const int l0 = c * QCH;
  const size_t hl = (size_t)hh * L_SEQ;

  __shared__ float Cst[48][64];
  __shared__ float Bst[48][64];
  __shared__ float Ss[64][65];
  __shared__ float Us[64][64];
  __shared__ float Dc[64], cfs[64], hds[64];

  if (tid < 64) {
    Dc[tid]  = cumD[hl + l0 + tid];
    cfs[tid] = cfac[hl + l0 + tid];
    hds[tid] = halfdt[hl + l0 + tid];
  }
  for (int i = tid; i < 64 * 16; i += 256) {
    int m = i >> 4, q = i & 15;
    *(float4*)&Us[m][q << 2] = *(const float4*)&U[(hl + l0 + m) * HEADDIM + (q << 2)];
  }

  // Phase A: S[t][m] = sum_n Crot[t][n]*Brot[m][n]
  float accS[4][4] = {};
  for (int nt = 0; nt < 4; ++nt) {
    int n0 = nt * 48;
    __syncthreads();
    for (int i = tid; i < 64 * 12; i += 256) {
      int t = i / 12, q = i - t * 12;
      float4 v = *(const float4*)&Crot[(hl + l0 + t) * DSTATE + n0 + (q << 2)];
      Cst[(q << 2) + 0][t] = v.x; Cst[(q << 2) + 1][t] = v.y;
      Cst[(q << 2) + 2][t] = v.z; Cst[(q << 2) + 3][t] = v.w;
      float4 w = *(const float4*)&Brot[(hl + l0 + t) * DSTATE + n0 + (q << 2)];
      Bst[(q << 2) + 0][t] = w.x; Bst[(q << 2) + 1][t] = w.y;
      Bst[(q << 2) + 2][t] = w.z; Bst[(q << 2) + 3][t] = w.w;
    }
    __syncthreads();
#pragma unroll 8
    for (int j = 0; j < 48; ++j) {
      const float4 cv = *(const float4*)&Cst[j][ty << 2];
      const float4 bv = *(const float4*)&Bst[j][tx << 2];
      float cc[4] = {cv.x, cv.y, cv.z, cv.w};
      float bb[4] = {bv.x, bv.y, bv.z, bv.w};
#pragma unroll
      for (int i = 0; i < 4; ++i)
#pragma unroll
        for (int k = 0; k < 4; ++k) accS[i][k] = fmaf(cc[i], bb[k], accS[i][k]);
    }
  }
  __syncthreads();

  // Phase B: weights -> Ss
#pragma unroll
  for (int i = 0; i < 4; ++i) {
    int t = (ty << 2) + i;
#pragma unroll
    for (int j2 = 0; j2 < 4; ++j2) {
      int m = (tx << 2) + j2;
      float w;
      if (m < t)       w = expf(Dc[t] - Dc[m]) * cfs[m];
      else if (m == t) w = hds[t];
      else             w = 0.f;
      Ss[t][m] = accS[i][j2] * w;
    }
  }
  __syncthreads();

  // Phase C: Y1 = Ss @ Us
  float accY[4][4] = {};
#pragma unroll 8
  for (int m = 0; m < 64; ++m) {
    const float4 uv = *(const float4*)&Us[m][tx << 2];
    float uu[4] = {uv.x, uv.y, uv.z, uv.w};
    float s0 = Ss[(ty << 2) + 0][m];
    float s1 = Ss[(ty << 2) + 1][m];
    float s2 = Ss[(ty << 2) + 2][m];
    float s3 = Ss[(ty << 2) + 3][m];
    float sv[4] = {s0, s1, s2, s3};
#pragma unroll
    for (int i = 0; i < 4; ++i)
#pragma unroll
      for (int j = 0; j < 4; ++j) accY[i][j] = fmaf(sv[i], uu[j], accY[i][j]);
  }

  // Phase D: Y2[t][p] = sum_n Crot[t][n] * Hstart[p][n]
  float accZ[4][4] = {};
  const size_t hcbase = ((size_t)(hh * NCHUNK + c)) * (HEADDIM * DSTATE);
  for (int nt = 0; nt < 4; ++nt) {
    int n0 = nt * 48;
    __syncthreads();
    for (int i = tid; i < 64 * 12; i += 256) {
      int t = i / 12, q = i - t * 12;
      float4 v = *(const float4*)&Crot[(hl + l0 + t) * DSTATE + n0 + (q << 2)];
      Cst[(q << 2) + 0][t] = v.x; Cst[(q << 2) + 1][t] = v.y;
      Cst[(q << 2) + 2][t] = v.z; Cst[(q << 2) + 3][t] = v.w;
      float4 w = *(const float4*)&Hs[hcbase + (size_t)t * DSTATE + n0 + (q << 2)];
      Bst[(q << 2) + 0][t] = w.x; Bst[(q << 2) + 1][t] = w.y;
      Bst[(q << 2) + 2][t] = w.z; Bst[(q << 2) + 3][t] = w.w;
    }
    __syncthreads();
#pragma unroll 8
    for (int j = 0; j < 48; ++j) {
      const float4 cv = *(const float4*)&Cst[j][ty << 2];
      const float4 hv = *(const float4*)&Bst[j][tx << 2];
      float cc[4] = {cv.x, cv.y, cv.z, cv.w};
      float hhv[4] = {hv.x, hv.y, hv.z, hv.w};
#pragma unroll
      for (int i = 0; i < 4; ++i)
#pragma unroll
        for (int k = 0; k < 4; ++k) accZ[i][k] = fmaf(cc[i], hhv[k], accZ[i][k]);
    }
  }

  // Phase E: combine + D*u + store
  float Dbase = (c > 0) ? cumD[hl + l0 - 1] : 0.f;
  float Dh = Dvec[hh];
#pragma unroll
  for (int i = 0; i < 4; ++i) {
    int t = (ty << 2) + i;
    float et = expf(Dc[t] - Dbase);
    const float4 uv = *(const float4*)&Us[t][tx << 2];
    float4 o;
    o.x = accY[i][0] + et * accZ[i][0] + Dh * uv.x;
    o.y = accY[i][1] + et * accZ[i][1] + Dh * uv.y;
    o.z = accY[i][2] + et * accZ[i][2] + Dh * uv.z;
    o.w = accY[i][3] + et * accZ[i][3] + Dh * uv.w;
    *(float4*)&Yout[(size_t)(l0 + t) * DINNER + hh * HEADDIM + (tx << 2)] = o;
  }
}

// ---------- K8: gate (silu) + RMSNorm over 1536 ----------
__global__ __launch_bounds__(256) void k_gate(const float* __restrict__ Y,
                                              const float* __restrict__ zx,
                                              const float* __restrict__ nw,
                                              float* __restrict__ G) {
  __shared__ float gbuf[DINNER];
  __shared__ float red[4];
  int l = blockIdx.x, tid = threadIdx.x;
  float ss = 0.f;
  for (int i = tid; i < DINNER; i += 256) {
    float y = Y[(size_t)l * DINNER + i];
    float z = zx[(size_t)l * DPROJ + i];
    float g = y * z / (1.f + expf(-z));
    gbuf[i] = g;
    ss += g * g;
  }
  ss = blockReduceSum256(ss, red);
  float r = rsqrtf(ss * (1.f / DINNER) + EPSF);
  for (int i = tid; i < DINNER; i += 256)
    G[(size_t)l * DINNER + i] = gbuf[i] * r * nw[i];
}

// ---------- K10: final RMSNorm + residual ----------
__global__ __launch_bounds__(256) void k_final(const float* __restrict__ x,
                                               const float* __restrict__ T,
                                               const float* __restrict__ post_scale,
                                               float* __restrict__ out) {
  __shared__ float red[4];
  int l = blockIdx.x, tid = threadIdx.x;
  const float* tr = T + (size_t)l * DMODEL;
  float v[3]; float ss = 0.f;
#pragma unroll
  for (int k = 0; k < 3; ++k) { v[k] = tr[tid + k * 256]; ss += v[k] * v[k]; }
  ss = blockReduceSum256(ss, red);
  float r = rsqrtf(ss * (1.f / DMODEL) + EPSF);
#pragma unroll
  for (int k = 0; k < 3; ++k) {
    int i = tid + k * 256;
    out[(size_t)l * DMODEL + i] = x[(size_t)l * DMODEL + i] + v[k] * r * (1.f + post_scale[i]);
  }
}

// ---------- launcher ----------
extern "C" void kernel_launch(void* const* d_in, const int* in_sizes, int n_in,
                              void* d_out, int out_size, void* d_ws, size_t ws_size,
                              hipStream_t stream) {
  const float* x      = (const float*)d_in[0];
  const float* pre_s  = (const float*)d_in[1];
  const float* W_in   = (const float*)d_in[2];
  const float* dt_b   = (const float*)d_in[3];
  const float* A_log  = (const float*)d_in[4];
  const float* omega  = (const float*)d_in[5];
  const float* Dvec   = (const float*)d_in[6];
  const float* nw     = (const float*)d_in[7];
  const float* W_out  = (const float*)d_in[8];
  const float* post_s = (const float*)d_in[9];
  float* out = (float*)d_out;

  float* ws = (float*)d_ws;
  size_t off = 0;
  auto nxt = [&](size_t n) { float* p = ws + off; off += n; return p; };
  float* ws_h   = nxt((size_t)L_SEQ * DMODEL);       // h; later reused as T (GEMM2 out)
  float* ws_zx  = nxt((size_t)L_SEQ * DPROJ);
  float* ws_hd  = nxt((size_t)NHEADS * L_SEQ);
  float* ws_cf  = nxt((size_t)NHEADS * L_SEQ);
  float* ws_cdt = nxt((size_t)NHEADS * L_SEQ);
  float* ws_cD  = nxt((size_t)NHEADS * L_SEQ);
  float* ws_Br  = nxt((size_t)NHEADS * L_SEQ * DSTATE);
  float* ws_Cr  = nxt((size_t)NHEADS * L_SEQ * DSTATE);
  float* ws_U   = nxt((size_t)NHEADS * L_SEQ * HEADDIM);
  float* ws_X   = nxt((size_t)NHEADS * NCHUNK * HEADDIM * DSTATE);
  float* ws_Hs  = nxt((size_t)NHEADS * NCHUNK * HEADDIM * DSTATE);
  float* ws_Y   = nxt((size_t)L_SEQ * DINNER);
  float* ws_G   = nxt((size_t)L_SEQ * DINNER);
  float* ws_T   = ws_h;

  k_prenorm<<<L_SEQ, 256, 0, stream>>>(x, pre_s, ws_h);
  k_sgemm64<<<dim3((DPROJ + 63) / 64, L_SEQ / 64), 256, 0, stream>>>(ws_h, W_in, ws_zx, L_SEQ, DPROJ, DMODEL);
  k_dtscan<<<NHEADS, 1024, 0, stream>>>(ws_zx, dt_b, A_log, ws_hd, ws_cf, ws_cdt, ws_cD);
  k_rotate<<<L_SEQ, 256, 0, stream>>>(ws_zx, ws_cdt, omega, ws_Br, ws_Cr, ws_U);
  k_chunkX<<<dim3(NCHUNK, NHEADS), 256, 0, stream>>>(ws_Br, ws_U, ws_cD, ws_cf, ws_X);
  k_statepass<<<NHEADS * 8, 256, 0, stream>>>(ws_X, ws_cD, ws_Hs);
  k_yout<<<dim3(NCHUNK, NHEADS), 256, 0, stream>>>(ws_Br, ws_Cr, ws_U, ws_Hs, ws_cD, ws_cf, ws_hd, Dvec, ws_Y);
  k_gate<<<L_SEQ, 256, 0, stream>>>(ws_Y, ws_zx, nw, ws_G);
  k_sgemm64<<<dim3(DMODEL / 64, L_SEQ / 64), 256, 0, stream>>>(ws_G, W_out, ws_T, L_SEQ, DMODEL, DINNER);
  k_final<<<L_SEQ, 256, 0, stream>>>(x, ws_T, post_s, out);
}

// Round 5
// 257.470 us; speedup vs baseline: 1.4465x; 1.4465x over previous
//
#include <hip/hip_runtime.h>
#include <cstdint>

#define L_SEQ   1024
#define DMODEL  768
#define DINNER  1536
#define NHEADS  24
#define HEADDIM 64
#define DSTATE  192
#define NPAIR   48
#define DPROJ   3480
#define NPADJ   3584      // DPROJ padded to 128 multiple for GEMM1
#define NCHUNK  16
#define QCH     64
#define EPSF    1e-6f

typedef __attribute__((ext_vector_type(8))) short short8;
typedef __attribute__((ext_vector_type(4))) float f32x4;

__device__ __forceinline__ unsigned short f2bf(float x) {
  union { float f; uint32_t u; } v; v.f = x;
  uint32_t r = (v.u + 0x7FFFu + ((v.u >> 16) & 1u)) >> 16;
  return (unsigned short)r;
}
__device__ __forceinline__ float bf2f(unsigned short b) {
  union { float f; uint32_t u; } v; v.u = ((uint32_t)b) << 16;
  return v.f;
}

__device__ __forceinline__ float blockReduceSum256(float v, float* red) {
#pragma unroll
  for (int m = 32; m; m >>= 1) v += __shfl_xor(v, m, 64);
  int wid = threadIdx.x >> 6, lane = threadIdx.x & 63;
  if (lane == 0) red[wid] = v;
  __syncthreads();
  float s = red[0] + red[1] + red[2] + red[3];
  __syncthreads();
  return s;
}

// ---------- K0: fp32 W[K][N] -> bf16 hi/lo transposed [Npad][K] (pad rows zero) ----------
__global__ __launch_bounds__(256) void k_cvtw(const float* __restrict__ W,
                                              unsigned short* __restrict__ Wh,
                                              unsigned short* __restrict__ Wl,
                                              int K, int N, int Npad) {
  __shared__ float tile[32][33];
  int n0 = blockIdx.x * 32, k0 = blockIdx.y * 32;
  int tr = threadIdx.x >> 3, tc4 = (threadIdx.x & 7) << 2;
  const float* wp = W + (size_t)(k0 + tr) * N + n0 + tc4;
  float4 v = make_float4(0.f, 0.f, 0.f, 0.f);
  if (n0 + tc4 + 3 < N) {
    v = *(const float4*)wp;
  } else {
    if (n0 + tc4     < N) v.x = wp[0];
    if (n0 + tc4 + 1 < N) v.y = wp[1];
    if (n0 + tc4 + 2 < N) v.z = wp[2];
    if (n0 + tc4 + 3 < N) v.w = wp[3];
  }
  tile[tr][tc4 + 0] = v.x; tile[tr][tc4 + 1] = v.y;
  tile[tr][tc4 + 2] = v.z; tile[tr][tc4 + 3] = v.w;
  __syncthreads();
  ushort4 oh, ol;
  float t0 = tile[tc4 + 0][tr], t1 = tile[tc4 + 1][tr];
  float t2 = tile[tc4 + 2][tr], t3 = tile[tc4 + 3][tr];
  oh.x = f2bf(t0); ol.x = f2bf(t0 - bf2f(oh.x));
  oh.y = f2bf(t1); ol.y = f2bf(t1 - bf2f(oh.y));
  oh.z = f2bf(t2); ol.z = f2bf(t2 - bf2f(oh.z));
  oh.w = f2bf(t3); ol.w = f2bf(t3 - bf2f(oh.w));
  size_t wi = (size_t)(n0 + tr) * K + k0 + tc4;
  *(ushort4*)&Wh[wi] = oh;
  *(ushort4*)&Wl[wi] = ol;
}

// ---------- K1: pre RMSNorm -> bf16 hi/lo ----------
__global__ __launch_bounds__(256) void k_prenorm(const float* __restrict__ x,
                                                 const float* __restrict__ pre_scale,
                                                 unsigned short* __restrict__ hh_,
                                                 unsigned short* __restrict__ hl_) {
  __shared__ float red[4];
  int l = blockIdx.x, tid = threadIdx.x;
  const float* xr = x + (size_t)l * DMODEL;
  float v[3]; float ss = 0.f;
#pragma unroll
  for (int k = 0; k < 3; ++k) { v[k] = xr[tid + k * 256]; ss += v[k] * v[k]; }
  ss = blockReduceSum256(ss, red);
  float r = rsqrtf(ss * (1.f / DMODEL) + EPSF);
#pragma unroll
  for (int k = 0; k < 3; ++k) {
    int i = tid + k * 256;
    float hv = v[k] * r * (1.f + pre_scale[i]);
    unsigned short hi = f2bf(hv);
    hh_[(size_t)l * DMODEL + i] = hi;
    hl_[(size_t)l * DMODEL + i] = f2bf(hv - bf2f(hi));
  }
}

// ---------- K2/K9: bf16x3 split MFMA GEMM (fp32-class accuracy) ----------
// A = Ah+Al [M][K], B = Bh+Bl [Npad][K] (transposed);  C ≈ AhBh + AhBl + AlBh
template<int BM, int BN, int TM, int TN>
__global__ __launch_bounds__(256) void k_gemm_bf16x3(
    const unsigned short* __restrict__ Ah, const unsigned short* __restrict__ Al,
    const unsigned short* __restrict__ Bh, const unsigned short* __restrict__ Bl,
    float* __restrict__ C, int N, int K, int ldc) {
  __shared__ unsigned short Ash[BM * 32];
  __shared__ unsigned short Asl[BM * 32];
  __shared__ unsigned short Bsh[BN * 32];
  __shared__ unsigned short Bsl[BN * 32];
  const int tid = threadIdx.x;
  const int lane = tid & 63, w = tid >> 6;
  const int wm = (w >> 1) * (TM * 16), wn = (w & 1) * (TN * 16);
  const int bm = blockIdx.y * BM, bn = blockIdx.x * BN;
  const int r15 = lane & 15, kg = lane >> 4;
  f32x4 acc[TM][TN] = {};
  for (int k0 = 0; k0 < K; k0 += 32) {
    __syncthreads();
#pragma unroll
    for (int ch = tid; ch < BM * 4; ch += 256) {
      int r = ch >> 2, kq = (ch & 3) << 3;
      size_t gi = (size_t)(bm + r) * K + k0 + kq;
      *(short8*)&Ash[r * 32 + kq] = *(const short8*)&Ah[gi];
      *(short8*)&Asl[r * 32 + kq] = *(const short8*)&Al[gi];
    }
#pragma unroll
    for (int ch = tid; ch < BN * 4; ch += 256) {
      int r = ch >> 2, kq = (ch & 3) << 3;
      size_t gi = (size_t)(bn + r) * K + k0 + kq;
      *(short8*)&Bsh[r * 32 + kq] = *(const short8*)&Bh[gi];
      *(short8*)&Bsl[r * 32 + kq] = *(const short8*)&Bl[gi];
    }
    __syncthreads();
    short8 afh[TM], afl[TM], bfh[TN], bfl[TN];
#pragma unroll
    for (int i = 0; i < TM; ++i) {
      int o = (wm + i * 16 + r15) * 32 + kg * 8;
      afh[i] = *(const short8*)&Ash[o];
      afl[i] = *(const short8*)&Asl[o];
    }
#pragma unroll
    for (int j = 0; j < TN; ++j) {
      int o = (wn + j * 16 + r15) * 32 + kg * 8;
      bfh[j] = *(const short8*)&Bsh[o];
      bfl[j] = *(const short8*)&Bsl[o];
    }
#pragma unroll
    for (int i = 0; i < TM; ++i)
#pragma unroll
      for (int j = 0; j < TN; ++j) {
        acc[i][j] = __builtin_amdgcn_mfma_f32_16x16x32_bf16(afh[i], bfh[j], acc[i][j], 0, 0, 0);
        acc[i][j] = __builtin_amdgcn_mfma_f32_16x16x32_bf16(afh[i], bfl[j], acc[i][j], 0, 0, 0);
        acc[i][j] = __builtin_amdgcn_mfma_f32_16x16x32_bf16(afl[i], bfh[j], acc[i][j], 0, 0, 0);
      }
  }
  const int crow = bm + wm + (lane >> 4) * 4;
  const int ccol = bn + wn + r15;
#pragma unroll
  for (int i = 0; i < TM; ++i)
#pragma unroll
    for (int j = 0; j < TN; ++j) {
      int col = ccol + j * 16;
      if (col < N) {
        float* cp = C + (size_t)(crow + i * 16) * ldc + col;
#pragma unroll
        for (int r = 0; r < 4; ++r) cp[(size_t)r * ldc] = acc[i][j][r];
      }
    }
}

// ---------- K3: dt softplus + inclusive cumsum (one block per head) ----------
__global__ __launch_bounds__(1024) void k_dtscan(const float* __restrict__ zx,
                                                 const float* __restrict__ dt_bias,
                                                 const float* __restrict__ A_log,
                                                 float* __restrict__ halfdt,
                                                 float* __restrict__ cfac,
                                                 float* __restrict__ cumdt,
                                                 float* __restrict__ cumD) {
  __shared__ float sdt[L_SEQ];
  __shared__ float sbuf[L_SEQ];
  int hh = blockIdx.x, l = threadIdx.x;
  float draw = zx[(size_t)l * DPROJ + 3456 + hh] + dt_bias[hh];
  float dt = (draw > 20.f) ? draw : log1pf(expf(draw));
  float Ah = -(expf(A_log[hh]) + 1e-4f);
  sdt[l] = dt;
  sbuf[l] = dt;
  __syncthreads();
  for (int off = 1; off < L_SEQ; off <<= 1) {
    float a = sbuf[l];
    float b = (l >= off) ? sbuf[l - off] : 0.f;
    __syncthreads();
    sbuf[l] = a + b;
    __syncthreads();
  }
  float cd = sbuf[l];
  float dnext = (l < L_SEQ - 1) ? sdt[l + 1] : 0.f;
  size_t idx = (size_t)hh * L_SEQ + l;
  halfdt[idx] = 0.5f * dt;
  cfac[idx]   = 0.5f * (dt + dnext);
  cumdt[idx]  = cd;
  cumD[idx]   = Ah * cd;
}

// ---------- K4: rotate B/C per head + gather U contiguous ----------
__global__ __launch_bounds__(256) void k_rotate(const float* __restrict__ zx,
                                                const float* __restrict__ cumdt,
                                                const float* __restrict__ omega,
                                                float* __restrict__ Brot,
                                                float* __restrict__ Crot,
                                                float* __restrict__ U) {
  int l = blockIdx.x, tid = threadIdx.x;
  const float* row = zx + (size_t)l * DPROJ;
  for (int i = tid; i < 384; i += 256) {
    float4 v = *(const float4*)(row + 1536 + i * 4);
    int hh = i >> 4;
    int p = (i & 15) << 2;
    *(float4*)&U[((size_t)(hh * L_SEQ + l)) * HEADDIM + p] = v;
  }
  for (int i = tid; i < NHEADS * 96; i += 256) {
    int hh = i / 96, j = i - hh * 96;
    int n = 2 * j;
    float b0 = row[3072 + n], b1 = row[3072 + n + 1];
    float c0 = row[3264 + n], c1 = row[3264 + n + 1];
    size_t base = ((size_t)(hh * L_SEQ + l)) * DSTATE + n;
    if (j < NPAIR) {
      float ph = cumdt[hh * L_SEQ + l] * omega[hh * NPAIR + j];
      float sp, cp;
      sincosf(ph, &sp, &cp);
      Brot[base]     =  b0 * cp + b1 * sp;
      Brot[base + 1] = -b0 * sp + b1 * cp;
      Crot[base]     =  c0 * cp - c1 * sp;
      Crot[base + 1] =  c0 * sp + c1 * cp;
    } else {
      Brot[base] = b0; Brot[base + 1] = b1;
      Crot[base] = c0; Crot[base + 1] = c1;
    }
  }
}

// ---------- K5: per-(head,chunk) state contribution X_c[p][n] ----------
__global__ __launch_bounds__(256) void k_chunkX(const float* __restrict__ Brot,
                                                const float* __restrict__ U,
                                                const float* __restrict__ cumD,
                                                const float* __restrict__ cfac,
                                                float* __restrict__ X) {
  const int c = blockIdx.x, hh = blockIdx.y;
  const int tid = threadIdx.x;
  const size_t hl = (size_t)hh * L_SEQ;
  const int l0 = c * QCH;
  __shared__ float Bs[QCH][DSTATE];
  __shared__ float su[QCH][HEADDIM];
  for (int i = tid; i < QCH * 48; i += 256) {
    int m = i / 48, q = i - m * 48;
    *(float4*)&Bs[m][q << 2] = *(const float4*)&Brot[(hl + l0 + m) * DSTATE + (q << 2)];
  }
  float dlast = cumD[hl + l0 + QCH - 1];
  for (int i = tid; i < QCH * 16; i += 256) {
    int m = i >> 4, q = i & 15;
    float s = expf(dlast - cumD[hl + l0 + m]) * cfac[hl + l0 + m];
    float4 v = *(const float4*)&U[(hl + l0 + m) * HEADDIM + (q << 2)];
    v.x *= s; v.y *= s; v.z *= s; v.w *= s;
    *(float4*)&su[m][q << 2] = v;
  }
  __syncthreads();
  const int ngrp = tid & 15, pgrp = tid >> 4;
  const int n0 = ngrp * 12, p0 = pgrp << 2;
  float acc[12][4] = {};
  for (int m = 0; m < QCH; ++m) {
    const float4 uv = *(const float4*)&su[m][p0];
    const float4 b0 = *(const float4*)&Bs[m][n0];
    const float4 b1 = *(const float4*)&Bs[m][n0 + 4];
    const float4 b2 = *(const float4*)&Bs[m][n0 + 8];
    float u4[4] = {uv.x, uv.y, uv.z, uv.w};
    float bb[12] = {b0.x, b0.y, b0.z, b0.w, b1.x, b1.y, b1.z, b1.w, b2.x, b2.y, b2.z, b2.w};
#pragma unroll
    for (int j = 0; j < 12; ++j)
#pragma unroll
      for (int i = 0; i < 4; ++i) acc[j][i] = fmaf(bb[j], u4[i], acc[j][i]);
  }
  const size_t obase = ((size_t)(hh * NCHUNK + c)) * (HEADDIM * DSTATE);
#pragma unroll
  for (int i = 0; i < 4; ++i)
#pragma unroll
    for (int j4 = 0; j4 < 3; ++j4)
      *(float4*)&X[obase + (size_t)(p0 + i) * DSTATE + n0 + j4 * 4] =
          make_float4(acc[j4 * 4 + 0][i], acc[j4 * 4 + 1][i], acc[j4 * 4 + 2][i], acc[j4 * 4 + 3][i]);
}

// ---------- K6: sequential chunk-state pass ----------
__global__ __launch_bounds__(256) void k_statepass(const float* __restrict__ X,
                                                   const float* __restrict__ cumD,
                                                   float* __restrict__ Hs) {
  int hh = blockIdx.x >> 3, part = blockIdx.x & 7;
  int tid = threadIdx.x;
  const size_t hl = (size_t)hh * L_SEQ;
  float Hc[6] = {0.f, 0.f, 0.f, 0.f, 0.f, 0.f};
  for (int c = 0; c < NCHUNK; ++c) {
    float r = 1.f;
    if (c > 0) r = expf(cumD[hl + c * QCH + QCH - 1] - cumD[hl + c * QCH - 1]);
    size_t base = ((size_t)(hh * NCHUNK + c)) * (HEADDIM * DSTATE) + part * 1536 + tid;
#pragma unroll
    for (int k = 0; k < 6; ++k) {
      Hs[base + k * 256] = Hc[k];
      Hc[k] = fmaf(r, Hc[k], X[base + k * 256]);
    }
  }
}

// ---------- K7: per-(head,chunk) output Y — conflict-free layout ----------
#define NP 100
__global__ __launch_bounds__(256) void k_yout(const float* __restrict__ Brot,
                                              const float* __restrict__ Crot,
                                              const float* __restrict__ U,
                                              const float* __restrict__ Hs,
                                              const float* __restrict__ cumD,
                                              const float* __restrict__ cfac,
                                              const float* __restrict__ halfdt,
                                              const float* __restrict__ Dvec,
                                              float* __restrict__ Yout) {
  const int c = blockIdx.x, hh = blockIdx.y;
  const int tid = threadIdx.x;
  const int tg = tid >> 4, tx = tid & 15;
  const int l0 = c * QCH;
  const size_t hl = (size_t)hh * L_SEQ;
  __shared__ float Cst[64][NP];
  __shared__ float Bst[64][NP];
  __shared__ float Ss[64][65];
  __shared__ float Dc[64], cfs[64], hds[64];
  if (tid < 64) {
    Dc[tid]  = cumD[hl + l0 + tid];
    cfs[tid] = cfac[hl + l0 + tid];
    hds[tid] = halfdt[hl + l0 + tid];
  }
  // Phase A: S[t][m] = sum_n Crot[t][n]*Brot[m][n], n in two halves of 96
  float accS[4][4] = {};
  for (int half = 0; half < 2; ++half) {
    __syncthreads();
    for (int idx = tid; idx < 64 * 24; idx += 256) {
      int t = idx / 24, q = (idx % 24) << 2;
      *(float4*)&Cst[t][q] = *(const float4*)&Crot[(hl + l0 + t) * DSTATE + 96 * half + q];
      *(float4*)&Bst[t][q] = *(const float4*)&Brot[(hl + l0 + t) * DSTATE + 96 * half + q];
    }
    __syncthreads();
#pragma unroll 4
    for (int nq = 0; nq < 96; nq += 4) {
      float4 cv[4], bv[4];
#pragma unroll
      for (int i = 0; i < 4; ++i) cv[i] = *(const float4*)&Cst[4 * tg + i][nq];
#pragma unroll
      for (int j = 0; j < 4; ++j) bv[j] = *(const float4*)&Bst[tx + 16 * j][nq];
#pragma unroll
      for (int i = 0; i < 4; ++i)
#pragma unroll
        for (int j = 0; j < 4; ++j)
          accS[i][j] += cv[i].x * bv[j].x + cv[i].y * bv[j].y +
                        cv[i].z * bv[j].z + cv[i].w * bv[j].w;
    }
  }
  __syncthreads();
  for (int idx = tid; idx < 64 * 16; idx += 256) {
    int m = idx >> 4, q = (idx & 15) << 2;
    *(float4*)&Bst[m][q] = *(const float4*)&U[(hl + l0 + m) * HEADDIM + q];
  }
#pragma unroll
  for (int i = 0; i < 4; ++i) {
    int t = 4 * tg + i;
#pragma unroll
    for (int j = 0; j < 4; ++j) {
      int m = tx + 16 * j;
      float w = 0.f;
      if (m < t)       w = expf(Dc[t] - Dc[m]) * cfs[m];
      else if (m == t) w = hds[t];
      Ss[t][m] = accS[i][j] * w;
    }
  }
  __syncthreads();
  // Phase C: Y1[t][p] = sum_m Ss[t][m] * U[m][p]
  float accY[4][4] = {};
  for (int m = 0; m < 64; ++m) {
    float sv[4], uv[4];
#pragma unroll
    for (int i = 0; i < 4; ++i) sv[i] = Ss[4 * tg + i][m];
#pragma unroll
    for (int j = 0; j < 4; ++j) uv[j] = Bst[m][tx + 16 * j];
#pragma unroll
    for (int i = 0; i < 4; ++i)
#pragma unroll
      for (int j = 0; j < 4; ++j) accY[i][j] = fmaf(sv[i], uv[j], accY[i][j]);
  }
  // Phase D: Z[t][p] = sum_n Crot[t][n] * Hs[p][n]
  float accZ[4][4] = {};
  const size_t hcbase = ((size_t)(hh * NCHUNK + c)) * (HEADDIM * DSTATE);
  for (int half = 0; half < 2; ++half) {
    __syncthreads();
    for (int idx = tid; idx < 64 * 24; idx += 256) {
      int t = idx / 24, q = (idx % 24) << 2;
      *(float4*)&Cst[t][q] = *(const float4*)&Crot[(hl + l0 + t) * DSTATE + 96 * half + q];
      *(float4*)&Bst[t][q] = *(const float4*)&Hs[hcbase + (size_t)t * DSTATE + 96 * half + q];
    }
    __syncthreads();
#pragma unroll 4
    for (int nq = 0; nq < 96; nq += 4) {
      float4 cv[4], hv[4];
#pragma unroll
      for (int i = 0; i < 4; ++i) cv[i] = *(const float4*)&Cst[4 * tg + i][nq];
#pragma unroll
      for (int j = 0; j < 4; ++j) hv[j] = *(const float4*)&Bst[tx + 16 * j][nq];
#pragma unroll
      for (int i = 0; i < 4; ++i)
#pragma unroll
        for (int j = 0; j < 4; ++j)
          accZ[i][j] += cv[i].x * hv[j].x + cv[i].y * hv[j].y +
                        cv[i].z * hv[j].z + cv[i].w * hv[j].w;
    }
  }
  // Phase E: combine + D*u + store
  float Dbase = (c > 0) ? cumD[hl + l0 - 1] : 0.f;
  float Dh = Dvec[hh];
#pragma unroll
  for (int i = 0; i < 4; ++i) {
    int t = 4 * tg + i;
    float et = expf(Dc[t] - Dbase);
#pragma unroll
    for (int j = 0; j < 4; ++j) {
      int p = tx + 16 * j;
      float u = U[(hl + l0 + t) * HEADDIM + p];
      Yout[(size_t)(l0 + t) * DINNER + hh * HEADDIM + p] =
          accY[i][j] + et * accZ[i][j] + Dh * u;
    }
  }
}

// ---------- K8: gate (silu) + RMSNorm over 1536 -> bf16 hi/lo ----------
__global__ __launch_bounds__(256) void k_gate(const float* __restrict__ Y,
                                              const float* __restrict__ zx,
                                              const float* __restrict__ nw,
                                              unsigned short* __restrict__ Gh,
                                              unsigned short* __restrict__ Gl) {
  __shared__ float gbuf[DINNER];
  __shared__ float red[4];
  int l = blockIdx.x, tid = threadIdx.x;
  float ss = 0.f;
  for (int i = tid; i < DINNER; i += 256) {
    float y = Y[(size_t)l * DINNER + i];
    float z = zx[(size_t)l * DPROJ + i];
    float g = y * z / (1.f + expf(-z));
    gbuf[i] = g;
    ss += g * g;
  }
  ss = blockReduceSum256(ss, red);
  float r = rsqrtf(ss * (1.f / DINNER) + EPSF);
  for (int i = tid; i < DINNER; i += 256) {
    float gv = gbuf[i] * r * nw[i];
    unsigned short hi = f2bf(gv);
    Gh[(size_t)l * DINNER + i] = hi;
    Gl[(size_t)l * DINNER + i] = f2bf(gv - bf2f(hi));
  }
}

// ---------- K10: final RMSNorm + residual ----------
__global__ __launch_bounds__(256) void k_final(const float* __restrict__ x,
                                               const float* __restrict__ T,
                                               const float* __restrict__ post_scale,
                                               float* __restrict__ out) {
  __shared__ float red[4];
  int l = blockIdx.x, tid = threadIdx.x;
  const float* tr = T + (size_t)l * DMODEL;
  float v[3]; float ss = 0.f;
#pragma unroll
  for (int k = 0; k < 3; ++k) { v[k] = tr[tid + k * 256]; ss += v[k] * v[k]; }
  ss = blockReduceSum256(ss, red);
  float r = rsqrtf(ss * (1.f / DMODEL) + EPSF);
#pragma unroll
  for (int k = 0; k < 3; ++k) {
    int i = tid + k * 256;
    out[(size_t)l * DMODEL + i] = x[(size_t)l * DMODEL + i] + v[k] * r * (1.f + post_scale[i]);
  }
}

// ---------- launcher ----------
extern "C" void kernel_launch(void* const* d_in, const int* in_sizes, int n_in,
                              void* d_out, int out_size, void* d_ws, size_t ws_size,
                              hipStream_t stream) {
  const float* x      = (const float*)d_in[0];
  const float* pre_s  = (const float*)d_in[1];
  const float* W_in   = (const float*)d_in[2];
  const float* dt_b   = (const float*)d_in[3];
  const float* A_log  = (const float*)d_in[4];
  const float* omega  = (const float*)d_in[5];
  const float* Dvec   = (const float*)d_in[6];
  const float* nw     = (const float*)d_in[7];
  const float* W_out  = (const float*)d_in[8];
  const float* post_s = (const float*)d_in[9];
  float* out = (float*)d_out;

  float* ws = (float*)d_ws;
  size_t off = 0;
  auto nxt = [&](size_t n) { float* p = ws + off; off += (n + 3) & ~(size_t)3; return p; };
  float* ws_zx  = nxt((size_t)L_SEQ * DPROJ);
  unsigned short* ws_hbh = (unsigned short*)nxt((size_t)L_SEQ * DMODEL / 2);
  unsigned short* ws_hbl = (unsigned short*)nxt((size_t)L_SEQ * DMODEL / 2);
  float* ws_hd  = nxt((size_t)NHEADS * L_SEQ);
  float* ws_cf  = nxt((size_t)NHEADS * L_SEQ);
  float* ws_cdt = nxt((size_t)NHEADS * L_SEQ);
  float* ws_cD  = nxt((size_t)NHEADS * L_SEQ);
  float* ws_Br  = nxt((size_t)NHEADS * L_SEQ * DSTATE);
  float* ws_Cr  = nxt((size_t)NHEADS * L_SEQ * DSTATE);
  float* ws_U   = nxt((size_t)NHEADS * L_SEQ * HEADDIM);
  float* ws_X   = nxt((size_t)NHEADS * NCHUNK * HEADDIM * DSTATE);
  float* ws_Hs  = nxt((size_t)NHEADS * NCHUNK * HEADDIM * DSTATE);
  float* ws_Y   = nxt((size_t)L_SEQ * DINNER);
  unsigned short* ws_Gh = (unsigned short*)nxt((size_t)L_SEQ * DINNER / 2);
  unsigned short* ws_Gl = (unsigned short*)nxt((size_t)L_SEQ * DINNER / 2);
  // aliases (lifetimes disjoint, same-stream serialization):
  // W1 hi/lo (NPADJ*768 bf16 = 1,376,256 floats each) live in ws_X (4,718,592 floats)
  unsigned short* ws_W1h = (unsigned short*)ws_X;
  unsigned short* ws_W1l = (unsigned short*)(ws_X + 1376256);
  // W2 hi/lo (768*1536 bf16 = 589,824 floats each) live in ws_Br (dead after k_yout)
  unsigned short* ws_W2h = (unsigned short*)ws_Br;
  unsigned short* ws_W2l = (unsigned short*)(ws_Br + 589824);
  // GEMM2 output T (1024*768 fp32) lives in ws_X (W1 and X both dead by then)
  float* ws_T = ws_X;

  k_cvtw<<<dim3(NPADJ / 32, DMODEL / 32), 256, 0, stream>>>(W_in, ws_W1h, ws_W1l, DMODEL, DPROJ, NPADJ);
  k_prenorm<<<L_SEQ, 256, 0, stream>>>(x, pre_s, ws_hbh, ws_hbl);
  k_gemm_bf16x3<128, 128, 4, 4><<<dim3(NPADJ / 128, L_SEQ / 128), 256, 0, stream>>>(
      ws_hbh, ws_hbl, ws_W1h, ws_W1l, ws_zx, DPROJ, DMODEL, DPROJ);
  k_dtscan<<<NHEADS, 1024, 0, stream>>>(ws_zx, dt_b, A_log, ws_hd, ws_cf, ws_cdt, ws_cD);
  k_rotate<<<L_SEQ, 256, 0, stream>>>(ws_zx, ws_cdt, omega, ws_Br, ws_Cr, ws_U);
  k_chunkX<<<dim3(NCHUNK, NHEADS), 256, 0, stream>>>(ws_Br, ws_U, ws_cD, ws_cf, ws_X);
  k_statepass<<<NHEADS * 8, 256, 0, stream>>>(ws_X, ws_cD, ws_Hs);
  k_yout<<<dim3(NCHUNK, NHEADS), 256, 0, stream>>>(ws_Br, ws_Cr, ws_U, ws_Hs, ws_cD, ws_cf, ws_hd, Dvec, ws_Y);
  k_cvtw<<<dim3(DMODEL / 32, DINNER / 32), 256, 0, stream>>>(W_out, ws_W2h, ws_W2l, DINNER, DMODEL, DMODEL);
  k_gate<<<L_SEQ, 256, 0, stream>>>(ws_Y, ws_zx, nw, ws_Gh, ws_Gl);
  k_gemm_bf16x3<64, 64, 2, 2><<<dim3(DMODEL / 64, L_SEQ / 64), 256, 0, stream>>>(
      ws_Gh, ws_Gl, ws_W2h, ws_W2l, ws_T, DMODEL, DINNER, DMODEL);
  k_final<<<L_SEQ, 256, 0, stream>>>(x, ws_T, post_s, out);
}

// Round 8
// 241.111 us; speedup vs baseline: 1.5447x; 1.0678x over previous
//
#include <hip/hip_runtime.h>
#include <cstdint>

#define L_SEQ   1024
#define DMODEL  768
#define DINNER  1536
#define NHEADS  24
#define HEADDIM 64
#define DSTATE  192
#define NPAIR   48
#define DPROJ   3480
#define NPADJ   3584      // DPROJ padded to 128 multiple for GEMM1
#define NCHUNK  16
#define QCH     64
#define EPSF    1e-6f

typedef __attribute__((ext_vector_type(8))) short short8;
typedef __attribute__((ext_vector_type(4))) float f32x4;

__device__ __forceinline__ unsigned short f2bf(float x) {
  union { float f; uint32_t u; } v; v.f = x;
  uint32_t r = (v.u + 0x7FFFu + ((v.u >> 16) & 1u)) >> 16;
  return (unsigned short)r;
}
__device__ __forceinline__ float bf2f(unsigned short b) {
  union { float f; uint32_t u; } v; v.u = ((uint32_t)b) << 16;
  return v.f;
}

__device__ __forceinline__ float blockReduceSum256(float v, float* red) {
#pragma unroll
  for (int m = 32; m; m >>= 1) v += __shfl_xor(v, m, 64);
  int wid = threadIdx.x >> 6, lane = threadIdx.x & 63;
  if (lane == 0) red[wid] = v;
  __syncthreads();
  float s = red[0] + red[1] + red[2] + red[3];
  __syncthreads();
  return s;
}

// ---------- K0: fp32 W[K][N] -> bf16 transposed [Npad][K]; lo part optional ----------
__global__ __launch_bounds__(256) void k_cvtw(const float* __restrict__ W,
                                              unsigned short* __restrict__ Wh,
                                              unsigned short* __restrict__ Wl,
                                              int K, int N, int Npad) {
  __shared__ float tile[32][33];
  int n0 = blockIdx.x * 32, k0 = blockIdx.y * 32;
  int tr = threadIdx.x >> 3, tc4 = (threadIdx.x & 7) << 2;
  const float* wp = W + (size_t)(k0 + tr) * N + n0 + tc4;
  float4 v = make_float4(0.f, 0.f, 0.f, 0.f);
  if (n0 + tc4 + 3 < N) {
    v = *(const float4*)wp;
  } else {
    if (n0 + tc4     < N) v.x = wp[0];
    if (n0 + tc4 + 1 < N) v.y = wp[1];
    if (n0 + tc4 + 2 < N) v.z = wp[2];
    if (n0 + tc4 + 3 < N) v.w = wp[3];
  }
  tile[tr][tc4 + 0] = v.x; tile[tr][tc4 + 1] = v.y;
  tile[tr][tc4 + 2] = v.z; tile[tr][tc4 + 3] = v.w;
  __syncthreads();
  float t0 = tile[tc4 + 0][tr], t1 = tile[tc4 + 1][tr];
  float t2 = tile[tc4 + 2][tr], t3 = tile[tc4 + 3][tr];
  ushort4 oh;
  oh.x = f2bf(t0); oh.y = f2bf(t1); oh.z = f2bf(t2); oh.w = f2bf(t3);
  size_t wi = (size_t)(n0 + tr) * K + k0 + tc4;
  *(ushort4*)&Wh[wi] = oh;
  if (Wl) {
    ushort4 ol;
    ol.x = f2bf(t0 - bf2f(oh.x));
    ol.y = f2bf(t1 - bf2f(oh.y));
    ol.z = f2bf(t2 - bf2f(oh.z));
    ol.w = f2bf(t3 - bf2f(oh.w));
    *(ushort4*)&Wl[wi] = ol;
  }
}

// ---------- K1: pre RMSNorm -> fp32 h (for dt GEMV) + bf16 h (for GEMM1) ----------
__global__ __launch_bounds__(256) void k_prenorm(const float* __restrict__ x,
                                                 const float* __restrict__ pre_scale,
                                                 float* __restrict__ hf,
                                                 unsigned short* __restrict__ hb) {
  __shared__ float red[4];
  int l = blockIdx.x, tid = threadIdx.x;
  const float* xr = x + (size_t)l * DMODEL;
  float v[3]; float ss = 0.f;
#pragma unroll
  for (int k = 0; k < 3; ++k) { v[k] = xr[tid + k * 256]; ss += v[k] * v[k]; }
  ss = blockReduceSum256(ss, red);
  float r = rsqrtf(ss * (1.f / DMODEL) + EPSF);
#pragma unroll
  for (int k = 0; k < 3; ++k) {
    int i = tid + k * 256;
    float hv = v[k] * r * (1.f + pre_scale[i]);
    hf[(size_t)l * DMODEL + i] = hv;
    hb[(size_t)l * DMODEL + i] = f2bf(hv);
  }
}

// ---------- K1b: fp32 GEMV for the 24 dt columns (keeps cumsum input exact) ----------
__global__ __launch_bounds__(256) void k_dtgemv(const float* __restrict__ hf,
                                                const float* __restrict__ W_in,
                                                float* __restrict__ dtr) {
  __shared__ float hs[DMODEL];
  __shared__ float part[NHEADS][8];
  int l = blockIdx.x, tid = threadIdx.x;
  for (int i = tid; i < DMODEL; i += 256) hs[i] = hf[(size_t)l * DMODEL + i];
  __syncthreads();
  if (tid < 192) {
    int hh = tid >> 3, seg = tid & 7;
    float s = 0.f;
    int k0 = seg * 96;
#pragma unroll 4
    for (int k = k0; k < k0 + 96; ++k)
      s = fmaf(hs[k], W_in[(size_t)k * DPROJ + 3456 + hh], s);
    part[hh][seg] = s;
  }
  __syncthreads();
  if (tid < NHEADS) {
    float s = 0.f;
#pragma unroll
    for (int q = 0; q < 8; ++q) s += part[tid][q];
    dtr[(size_t)l * NHEADS + tid] = s;
  }
}

// ---------- K2: plain bf16 MFMA GEMM (GEMM1) ----------
template<int BM, int BN, int TM, int TN>
__global__ __launch_bounds__(256) void k_gemm_bf16(
    const unsigned short* __restrict__ A,
    const unsigned short* __restrict__ Bt,
    float* __restrict__ C,
    int N, int K, int ldc) {
  __shared__ unsigned short As[BM * 32];
  __shared__ unsigned short Bs[BN * 32];
  const int tid = threadIdx.x;
  const int lane = tid & 63, w = tid >> 6;
  const int wm = (w >> 1) * (TM * 16), wn = (w & 1) * (TN * 16);
  const int bm = blockIdx.y * BM, bn = blockIdx.x * BN;
  const int r15 = lane & 15, kg = lane >> 4;
  f32x4 acc[TM][TN] = {};
  for (int k0 = 0; k0 < K; k0 += 32) {
    __syncthreads();
#pragma unroll
    for (int ch = tid; ch < BM * 4; ch += 256) {
      int r = ch >> 2, kq = (ch & 3) << 3;
      *(short8*)&As[r * 32 + kq] = *(const short8*)&A[(size_t)(bm + r) * K + k0 + kq];
    }
#pragma unroll
    for (int ch = tid; ch < BN * 4; ch += 256) {
      int r = ch >> 2, kq = (ch & 3) << 3;
      *(short8*)&Bs[r * 32 + kq] = *(const short8*)&Bt[(size_t)(bn + r) * K + k0 + kq];
    }
    __syncthreads();
    short8 af[TM], bfr[TN];
#pragma unroll
    for (int i = 0; i < TM; ++i)
      af[i] = *(const short8*)&As[(wm + i * 16 + r15) * 32 + kg * 8];
#pragma unroll
    for (int j = 0; j < TN; ++j)
      bfr[j] = *(const short8*)&Bs[(wn + j * 16 + r15) * 32 + kg * 8];
#pragma unroll
    for (int i = 0; i < TM; ++i)
#pragma unroll
      for (int j = 0; j < TN; ++j)
        acc[i][j] = __builtin_amdgcn_mfma_f32_16x16x32_bf16(af[i], bfr[j], acc[i][j], 0, 0, 0);
  }
  const int crow = bm + wm + (lane >> 4) * 4;
  const int ccol = bn + wn + r15;
#pragma unroll
  for (int i = 0; i < TM; ++i)
#pragma unroll
    for (int j = 0; j < TN; ++j) {
      int col = ccol + j * 16;
      if (col < N) {
        float* cp = C + (size_t)(crow + i * 16) * ldc + col;
#pragma unroll
        for (int r = 0; r < 4; ++r) cp[(size_t)r * ldc] = acc[i][j][r];
      }
    }
}

// ---------- K9: bf16x3 split MFMA GEMM (GEMM2, fp32-class accuracy) ----------
template<int BM, int BN, int TM, int TN>
__global__ __launch_bounds__(256) void k_gemm_bf16x3(
    const unsigned short* __restrict__ Ah, const unsigned short* __restrict__ Al,
    const unsigned short* __restrict__ Bh, const unsigned short* __restrict__ Bl,
    float* __restrict__ C, int N, int K, int ldc) {
  __shared__ unsigned short Ash[BM * 32];
  __shared__ unsigned short Asl[BM * 32];
  __shared__ unsigned short Bsh[BN * 32];
  __shared__ unsigned short Bsl[BN * 32];
  const int tid = threadIdx.x;
  const int lane = tid & 63, w = tid >> 6;
  const int wm = (w >> 1) * (TM * 16), wn = (w & 1) * (TN * 16);
  const int bm = blockIdx.y * BM, bn = blockIdx.x * BN;
  const int r15 = lane & 15, kg = lane >> 4;
  f32x4 acc[TM][TN] = {};
  for (int k0 = 0; k0 < K; k0 += 32) {
    __syncthreads();
#pragma unroll
    for (int ch = tid; ch < BM * 4; ch += 256) {
      int r = ch >> 2, kq = (ch & 3) << 3;
      size_t gi = (size_t)(bm + r) * K + k0 + kq;
      *(short8*)&Ash[r * 32 + kq] = *(const short8*)&Ah[gi];
      *(short8*)&Asl[r * 32 + kq] = *(const short8*)&Al[gi];
    }
#pragma unroll
    for (int ch = tid; ch < BN * 4; ch += 256) {
      int r = ch >> 2, kq = (ch & 3) << 3;
      size_t gi = (size_t)(bn + r) * K + k0 + kq;
      *(short8*)&Bsh[r * 32 + kq] = *(const short8*)&Bh[gi];
      *(short8*)&Bsl[r * 32 + kq] = *(const short8*)&Bl[gi];
    }
    __syncthreads();
    short8 afh[TM], afl[TM], bfh[TN], bfl[TN];
#pragma unroll
    for (int i = 0; i < TM; ++i) {
      int o = (wm + i * 16 + r15) * 32 + kg * 8;
      afh[i] = *(const short8*)&Ash[o];
      afl[i] = *(const short8*)&Asl[o];
    }
#pragma unroll
    for (int j = 0; j < TN; ++j) {
      int o = (wn + j * 16 + r15) * 32 + kg * 8;
      bfh[j] = *(const short8*)&Bsh[o];
      bfl[j] = *(const short8*)&Bsl[o];
    }
#pragma unroll
    for (int i = 0; i < TM; ++i)
#pragma unroll
      for (int j = 0; j < TN; ++j) {
        acc[i][j] = __builtin_amdgcn_mfma_f32_16x16x32_bf16(afh[i], bfh[j], acc[i][j], 0, 0, 0);
        acc[i][j] = __builtin_amdgcn_mfma_f32_16x16x32_bf16(afh[i], bfl[j], acc[i][j], 0, 0, 0);
        acc[i][j] = __builtin_amdgcn_mfma_f32_16x16x32_bf16(afl[i], bfh[j], acc[i][j], 0, 0, 0);
      }
  }
  const int crow = bm + wm + (lane >> 4) * 4;
  const int ccol = bn + wn + r15;
#pragma unroll
  for (int i = 0; i < TM; ++i)
#pragma unroll
    for (int j = 0; j < TN; ++j) {
      int col = ccol + j * 16;
      if (col < N) {
        float* cp = C + (size_t)(crow + i * 16) * ldc + col;
#pragma unroll
        for (int r = 0; r < 4; ++r) cp[(size_t)r * ldc] = acc[i][j][r];
      }
    }
}

// ---------- K3: dt softplus + cumsum, shuffle scan (4 elem/thread, 1 barrier) ----------
__global__ __launch_bounds__(256) void k_dtscan(const float* __restrict__ dtr,
                                                const float* __restrict__ dt_bias,
                                                const float* __restrict__ A_log,
                                                float* __restrict__ halfdt,
                                                float* __restrict__ cfac,
                                                float* __restrict__ cumdt,
                                                float* __restrict__ cumD) {
  __shared__ float sdt[L_SEQ];
  __shared__ float wsum[4];
  int hh = blockIdx.x, tid = threadIdx.x;
  int lane = tid & 63, wid = tid >> 6;
  float bias = dt_bias[hh];
  float Ah = -(expf(A_log[hh]) + 1e-4f);
  int l0 = tid * 4;
  float d[4], e[4];
#pragma unroll
  for (int k = 0; k < 4; ++k) {
    float draw = dtr[(size_t)(l0 + k) * NHEADS + hh] + bias;
    d[k] = (draw > 20.f) ? draw : log1pf(expf(draw));
    sdt[l0 + k] = d[k];
  }
  e[0] = d[0]; e[1] = e[0] + d[1]; e[2] = e[1] + d[2]; e[3] = e[2] + d[3];
  float tot = e[3];
  float s = tot;
#pragma unroll
  for (int off = 1; off < 64; off <<= 1) {
    float n = __shfl_up(s, off, 64);
    if (lane >= off) s += n;
  }
  if (lane == 63) wsum[wid] = s;
  __syncthreads();
  float woff = 0.f;
#pragma unroll
  for (int q = 0; q < 4; ++q) woff += (q < wid) ? wsum[q] : 0.f;
  float excl = woff + s - tot;
  float4 o_hd, o_cf, o_cd, o_cD;
  float cd0 = excl + e[0], cd1 = excl + e[1], cd2 = excl + e[2], cd3 = excl + e[3];
  float dnext3 = (l0 + 3 < L_SEQ - 1) ? sdt[l0 + 4] : 0.f;
  o_hd = make_float4(0.5f * d[0], 0.5f * d[1], 0.5f * d[2], 0.5f * d[3]);
  o_cf = make_float4(0.5f * (d[0] + d[1]), 0.5f * (d[1] + d[2]),
                     0.5f * (d[2] + d[3]), 0.5f * (d[3] + dnext3));
  o_cd = make_float4(cd0, cd1, cd2, cd3);
  o_cD = make_float4(Ah * cd0, Ah * cd1, Ah * cd2, Ah * cd3);
  size_t idx = (size_t)hh * L_SEQ + l0;
  *(float4*)&halfdt[idx] = o_hd;
  *(float4*)&cfac[idx]   = o_cf;
  *(float4*)&cumdt[idx]  = o_cd;
  *(float4*)&cumD[idx]   = o_cD;
}

// ---------- K4: rotate B/C per head + gather U contiguous ----------
__global__ __launch_bounds__(256) void k_rotate(const float* __restrict__ zx,
                                                const float* __restrict__ cumdt,
                                                const float* __restrict__ omega,
                                                float* __restrict__ Brot,
                                                float* __restrict__ Crot,
                                                float* __restrict__ U) {
  int l = blockIdx.x, tid = threadIdx.x;
  const float* row = zx + (size_t)l * DPROJ;
  for (int i = tid; i < 384; i += 256) {
    float4 v = *(const float4*)(row + 1536 + i * 4);
    int hh = i >> 4;
    int p = (i & 15) << 2;
    *(float4*)&U[((size_t)(hh * L_SEQ + l)) * HEADDIM + p] = v;
  }
  for (int i = tid; i < NHEADS * 96; i += 256) {
    int hh = i / 96, j = i - hh * 96;
    int n = 2 * j;
    float b0 = row[3072 + n], b1 = row[3072 + n + 1];
    float c0 = row[3264 + n], c1 = row[3264 + n + 1];
    size_t base = ((size_t)(hh * L_SEQ + l)) * DSTATE + n;
    if (j < NPAIR) {
      float ph = cumdt[hh * L_SEQ + l] * omega[hh * NPAIR + j];
      float sp, cp;
      sincosf(ph, &sp, &cp);
      Brot[base]     =  b0 * cp + b1 * sp;
      Brot[base + 1] = -b0 * sp + b1 * cp;
      Crot[base]     =  c0 * cp - c1 * sp;
      Crot[base + 1] =  c0 * sp + c1 * cp;
    } else {
      Brot[base] = b0; Brot[base + 1] = b1;
      Crot[base] = c0; Crot[base + 1] = c1;
    }
  }
}

// ---------- K5: per-(head,chunk) state contribution X_c[p][n] ----------
__global__ __launch_bounds__(256) void k_chunkX(const float* __restrict__ Brot,
                                                const float* __restrict__ U,
                                                const float* __restrict__ cumD,
                                                const float* __restrict__ cfac,
                                                float* __restrict__ X) {
  const int c = blockIdx.x, hh = blockIdx.y;
  const int tid = threadIdx.x;
  const size_t hl = (size_t)hh * L_SEQ;
  const int l0 = c * QCH;
  __shared__ float Bs[QCH][DSTATE];
  __shared__ float su[QCH][HEADDIM];
  for (int i = tid; i < QCH * 48; i += 256) {
    int m = i / 48, q = i - m * 48;
    *(float4*)&Bs[m][q << 2] = *(const float4*)&Brot[(hl + l0 + m) * DSTATE + (q << 2)];
  }
  float dlast = cumD[hl + l0 + QCH - 1];
  for (int i = tid; i < QCH * 16; i += 256) {
    int m = i >> 4, q = i & 15;
    float s = expf(dlast - cumD[hl + l0 + m]) * cfac[hl + l0 + m];
    float4 v = *(const float4*)&U[(hl + l0 + m) * HEADDIM + (q << 2)];
    v.x *= s; v.y *= s; v.z *= s; v.w *= s;
    *(float4*)&su[m][q << 2] = v;
  }
  __syncthreads();
  const int ngrp = tid & 15, pgrp = tid >> 4;
  const int n0 = ngrp * 12, p0 = pgrp << 2;
  float acc[12][4] = {};
  for (int m = 0; m < QCH; ++m) {
    const float4 uv = *(const float4*)&su[m][p0];
    const float4 b0 = *(const float4*)&Bs[m][n0];
    const float4 b1 = *(const float4*)&Bs[m][n0 + 4];
    const float4 b2 = *(const float4*)&Bs[m][n0 + 8];
    float u4[4] = {uv.x, uv.y, uv.z, uv.w};
    float bb[12] = {b0.x, b0.y, b0.z, b0.w, b1.x, b1.y, b1.z, b1.w, b2.x, b2.y, b2.z, b2.w};
#pragma unroll
    for (int j = 0; j < 12; ++j)
#pragma unroll
      for (int i = 0; i < 4; ++i) acc[j][i] = fmaf(bb[j], u4[i], acc[j][i]);
  }
  const size_t obase = ((size_t)(hh * NCHUNK + c)) * (HEADDIM * DSTATE);
#pragma unroll
  for (int i = 0; i < 4; ++i)
#pragma unroll
    for (int j4 = 0; j4 < 3; ++j4)
      *(float4*)&X[obase + (size_t)(p0 + i) * DSTATE + n0 + j4 * 4] =
          make_float4(acc[j4 * 4 + 0][i], acc[j4 * 4 + 1][i], acc[j4 * 4 + 2][i], acc[j4 * 4 + 3][i]);
}

// ---------- K6: sequential chunk-state pass ----------
__global__ __launch_bounds__(256) void k_statepass(const float* __restrict__ X,
                                                   const float* __restrict__ cumD,
                                                   float* __restrict__ Hs) {
  int hh = blockIdx.x >> 3, part = blockIdx.x & 7;
  int tid = threadIdx.x;
  const size_t hl = (size_t)hh * L_SEQ;
  float Hc[6] = {0.f, 0.f, 0.f, 0.f, 0.f, 0.f};
  for (int c = 0; c < NCHUNK; ++c) {
    float r = 1.f;
    if (c > 0) r = expf(cumD[hl + c * QCH + QCH - 1] - cumD[hl + c * QCH - 1]);
    size_t base = ((size_t)(hh * NCHUNK + c)) * (HEADDIM * DSTATE) + part * 1536 + tid;
#pragma unroll
    for (int k = 0; k < 6; ++k) {
      Hs[base + k * 256] = Hc[k];
      Hc[k] = fmaf(r, Hc[k], X[base + k * 256]);
    }
  }
}

// ---------- K7: per-(head,chunk) output Y via MFMA ----------
// S = Crot·Brot^T (64x64x192), weights in fp32, Y1 = Sw·U^T (64x64x64),
// Z = Crot·Hs^T (64x64x192), out = Y1 + exp(Dc-Dbase)*Z + D*u
#define YP 104   // bf16 pad stride for 96-col K tiles (2-way conflict free)
#define SP 72    // bf16 pad stride for 64-col tiles
__global__ __launch_bounds__(256) void k_yout_mfma(
    const float* __restrict__ Brot, const float* __restrict__ Crot,
    const float* __restrict__ U,    const float* __restrict__ Hs,
    const float* __restrict__ cumD, const float* __restrict__ cfac,
    const float* __restrict__ halfdt, const float* __restrict__ Dvec,
    float* __restrict__ Yout) {
  const int c = blockIdx.x, hh = blockIdx.y;
  const int tid = threadIdx.x;
  const int lane = tid & 63, w = tid >> 6;
  const int wr = w >> 1, wc = w & 1;
  const int r15 = lane & 15, kg = lane >> 4;
  const int l0 = c * QCH;
  const size_t hl = (size_t)hh * L_SEQ;

  __shared__ unsigned short Cs[64][YP];
  __shared__ unsigned short Bs[64][YP];   // reused for Hs tiles in Z phase
  __shared__ unsigned short Ss[64][SP];
  __shared__ unsigned short Ut[64][SP];
  __shared__ float Dc[64], cfs[64], hds[64];

  if (tid < 64) {
    Dc[tid]  = cumD[hl + l0 + tid];
    cfs[tid] = cfac[hl + l0 + tid];
    hds[tid] = halfdt[hl + l0 + tid];
  }
  // stage U transposed -> Ut[p][m]
  for (int idx = tid; idx < 64 * 64; idx += 256) {
    int m = idx >> 6, p = idx & 63;
    Ut[p][m] = f2bf(U[(hl + l0 + m) * HEADDIM + p]);
  }

  // Phase A: S = C · B^T over K=192 in two halves of 96
  f32x4 accS[2][2] = {};
  for (int half = 0; half < 2; ++half) {
    __syncthreads();
    for (int idx = tid; idx < 64 * 24; idx += 256) {
      int t = idx / 24, q = (idx % 24) << 2;
      float4 cv = *(const float4*)&Crot[(hl + l0 + t) * DSTATE + 96 * half + q];
      float4 bv = *(const float4*)&Brot[(hl + l0 + t) * DSTATE + 96 * half + q];
      Cs[t][q + 0] = f2bf(cv.x); Cs[t][q + 1] = f2bf(cv.y);
      Cs[t][q + 2] = f2bf(cv.z); Cs[t][q + 3] = f2bf(cv.w);
      Bs[t][q + 0] = f2bf(bv.x); Bs[t][q + 1] = f2bf(bv.y);
      Bs[t][q + 2] = f2bf(bv.z); Bs[t][q + 3] = f2bf(bv.w);
    }
    __syncthreads();
#pragma unroll
    for (int kk = 0; kk < 3; ++kk) {
      short8 af[2], bfr[2];
#pragma unroll
      for (int i = 0; i < 2; ++i)
        af[i] = *(const short8*)&Cs[wr * 32 + i * 16 + r15][kk * 32 + kg * 8];
#pragma unroll
      for (int j = 0; j < 2; ++j)
        bfr[j] = *(const short8*)&Bs[wc * 32 + j * 16 + r15][kk * 32 + kg * 8];
#pragma unroll
      for (int i = 0; i < 2; ++i)
#pragma unroll
        for (int j = 0; j < 2; ++j)
          accS[i][j] = __builtin_amdgcn_mfma_f32_16x16x32_bf16(af[i], bfr[j], accS[i][j], 0, 0, 0);
    }
  }
  // apply causal trapezoid weights in fp32, write Sw to LDS as bf16
#pragma unroll
  for (int i = 0; i < 2; ++i)
#pragma unroll
    for (int j = 0; j < 2; ++j)
#pragma unroll
      for (int r = 0; r < 4; ++r) {
        int t = wr * 32 + i * 16 + kg * 4 + r;
        int m = wc * 32 + j * 16 + r15;
        float wgt = 0.f;
        if (m < t)       wgt = __expf(Dc[t] - Dc[m]) * cfs[m];
        else if (m == t) wgt = hds[t];
        Ss[t][m] = f2bf(accS[i][j][r] * wgt);
      }

  // Phase B: Z = C · Hs^T over K=192 in two halves (Bs <- Hs tile rows = p)
  f32x4 accZ[2][2] = {};
  const size_t hcb = ((size_t)(hh * NCHUNK + c)) * (HEADDIM * DSTATE);
  for (int half = 0; half < 2; ++half) {
    __syncthreads();
    for (int idx = tid; idx < 64 * 24; idx += 256) {
      int t = idx / 24, q = (idx % 24) << 2;
      float4 cv = *(const float4*)&Crot[(hl + l0 + t) * DSTATE + 96 * half + q];
      float4 hv = *(const float4*)&Hs[hcb + (size_t)t * DSTATE + 96 * half + q];
      Cs[t][q + 0] = f2bf(cv.x); Cs[t][q + 1] = f2bf(cv.y);
      Cs[t][q + 2] = f2bf(cv.z); Cs[t][q + 3] = f2bf(cv.w);
      Bs[t][q + 0] = f2bf(hv.x); Bs[t][q + 1] = f2bf(hv.y);
      Bs[t][q + 2] = f2bf(hv.z); Bs[t][q + 3] = f2bf(hv.w);
    }
    __syncthreads();
#pragma unroll
    for (int kk = 0; kk < 3; ++kk) {
      short8 af[2], bfr[2];
#pragma unroll
      for (int i = 0; i < 2; ++i)
        af[i] = *(const short8*)&Cs[wr * 32 + i * 16 + r15][kk * 32 + kg * 8];
#pragma unroll
      for (int j = 0; j < 2; ++j)
        bfr[j] = *(const short8*)&Bs[wc * 32 + j * 16 + r15][kk * 32 + kg * 8];
#pragma unroll
      for (int i = 0; i < 2; ++i)
#pragma unroll
        for (int j = 0; j < 2; ++j)
          accZ[i][j] = __builtin_amdgcn_mfma_f32_16x16x32_bf16(af[i], bfr[j], accZ[i][j], 0, 0, 0);
    }
  }

  // Phase C: Y1 = Sw · Ut^T (K = 64) — Ss/Ut writes are covered by Z-phase barriers
  f32x4 accY[2][2] = {};
#pragma unroll
  for (int kk = 0; kk < 2; ++kk) {
    short8 af[2], bfr[2];
#pragma unroll
    for (int i = 0; i < 2; ++i)
      af[i] = *(const short8*)&Ss[wr * 32 + i * 16 + r15][kk * 32 + kg * 8];
#pragma unroll
    for (int j = 0; j < 2; ++j)
      bfr[j] = *(const short8*)&Ut[wc * 32 + j * 16 + r15][kk * 32 + kg * 8];
#pragma unroll
    for (int i = 0; i < 2; ++i)
#pragma unroll
      for (int j = 0; j < 2; ++j)
        accY[i][j] = __builtin_amdgcn_mfma_f32_16x16x32_bf16(af[i], bfr[j], accY[i][j], 0, 0, 0);
  }

  // Epilogue
  float Dbase = (c > 0) ? cumD[hl + l0 - 1] : 0.f;
  float Dh = Dvec[hh];
#pragma unroll
  for (int i = 0; i < 2; ++i)
#pragma unroll
    for (int r = 0; r < 4; ++r) {
      int t = wr * 32 + i * 16 + kg * 4 + r;
      float et = __expf(Dc[t] - Dbase);
#pragma unroll
      for (int j = 0; j < 2; ++j) {
        int p = wc * 32 + j * 16 + r15;
        float u = U[(hl + l0 + t) * HEADDIM + p];
        Yout[(size_t)(l0 + t) * DINNER + hh * HEADDIM + p] =
            accY[i][j][r] + et * accZ[i][j][r] + Dh * u;
      }
    }
}

// ---------- K8: gate (silu) + RMSNorm over 1536 -> bf16 hi/lo ----------
__global__ __launch_bounds__(256) void k_gate(const float* __restrict__ Y,
                                              const float* __restrict__ zx,
                                              const float* __restrict__ nw,
                                              unsigned short* __restrict__ Gh,
                                              unsigned short* __restrict__ Gl) {
  __shared__ float gbuf[DINNER];
  __shared__ float red[4];
  int l = blockIdx.x, tid = threadIdx.x;
  float ss = 0.f;
  for (int i = tid; i < DINNER; i += 256) {
    float y = Y[(size_t)l * DINNER + i];
    float z = zx[(size_t)l * DPROJ + i];
    float g = y * z / (1.f + expf(-z));
    gbuf[i] = g;
    ss += g * g;
  }
  ss = blockReduceSum256(ss, red);
  float r = rsqrtf(ss * (1.f / DINNER) + EPSF);
  for (int i = tid; i < DINNER; i += 256) {
    float gv = gbuf[i] * r * nw[i];
    unsigned short hi = f2bf(gv);
    Gh[(size_t)l * DINNER + i] = hi;
    Gl[(size_t)l * DINNER + i] = f2bf(gv - bf2f(hi));
  }
}

// ---------- K10: final RMSNorm + residual ----------
__global__ __launch_bounds__(256) void k_final(const float* __restrict__ x,
                                               const float* __restrict__ T,
                                               const float* __restrict__ post_scale,
                                               float* __restrict__ out) {
  __shared__ float red[4];
  int l = blockIdx.x, tid = threadIdx.x;
  const float* tr = T + (size_t)l * DMODEL;
  float v[3]; float ss = 0.f;
#pragma unroll
  for (int k = 0; k < 3; ++k) { v[k] = tr[tid + k * 256]; ss += v[k] * v[k]; }
  ss = blockReduceSum256(ss, red);
  float r = rsqrtf(ss * (1.f / DMODEL) + EPSF);
#pragma unroll
  for (int k = 0; k < 3; ++k) {
    int i = tid + k * 256;
    out[(size_t)l * DMODEL + i] = x[(size_t)l * DMODEL + i] + v[k] * r * (1.f + post_scale[i]);
  }
}

// ---------- launcher ----------
extern "C" void kernel_launch(void* const* d_in, const int* in_sizes, int n_in,
                              void* d_out, int out_size, void* d_ws, size_t ws_size,
                              hipStream_t stream) {
  const float* x      = (const float*)d_in[0];
  const float* pre_s  = (const float*)d_in[1];
  const float* W_in   = (const float*)d_in[2];
  const float* dt_b   = (const float*)d_in[3];
  const float* A_log  = (const float*)d_in[4];
  const float* omega  = (const float*)d_in[5];
  const float* Dvec   = (const float*)d_in[6];
  const float* nw     = (const float*)d_in[7];
  const float* W_out  = (const float*)d_in[8];
  const float* post_s = (const float*)d_in[9];
  float* out = (float*)d_out;

  float* ws = (float*)d_ws;
  size_t off = 0;
  auto nxt = [&](size_t n) { float* p = ws + off; off += (n + 3) & ~(size_t)3; return p; };
  float* ws_zx  = nxt((size_t)L_SEQ * DPROJ);
  float* ws_hf  = nxt((size_t)L_SEQ * DMODEL);
  unsigned short* ws_hb = (unsigned short*)nxt((size_t)L_SEQ * DMODEL / 2);
  float* ws_dtr = nxt((size_t)L_SEQ * NHEADS);
  float* ws_hd  = nxt((size_t)NHEADS * L_SEQ);
  float* ws_cf  = nxt((size_t)NHEADS * L_SEQ);
  float* ws_cdt = nxt((size_t)NHEADS * L_SEQ);
  float* ws_cD  = nxt((size_t)NHEADS * L_SEQ);
  float* ws_Br  = nxt((size_t)NHEADS * L_SEQ * DSTATE);
  float* ws_Cr  = nxt((size_t)NHEADS * L_SEQ * DSTATE);
  float* ws_U   = nxt((size_t)NHEADS * L_SEQ * HEADDIM);
  float* ws_X   = nxt((size_t)NHEADS * NCHUNK * HEADDIM * DSTATE);
  float* ws_Hs  = nxt((size_t)NHEADS * NCHUNK * HEADDIM * DSTATE);
  float* ws_Y   = nxt((size_t)L_SEQ * DINNER);
  unsigned short* ws_Gh = (unsigned short*)nxt((size_t)L_SEQ * DINNER / 2);
  unsigned short* ws_Gl = (unsigned short*)nxt((size_t)L_SEQ * DINNER / 2);
  // aliases (lifetimes disjoint, same-stream serialization):
  unsigned short* ws_W1h = (unsigned short*)ws_X;   // [NPADJ][768] bf16; dead before chunkX writes X
  unsigned short* ws_W2h = (unsigned short*)ws_Br;  // [768*1536] bf16 hi; Br dead after k_yout
  unsigned short* ws_W2l = (unsigned short*)(ws_Br + 589824);
  float* ws_T = ws_X;                               // GEMM2 out; X dead after statepass

  k_cvtw<<<dim3(NPADJ / 32, DMODEL / 32), 256, 0, stream>>>(W_in, ws_W1h, (unsigned short*)nullptr, DMODEL, DPROJ, NPADJ);
  k_prenorm<<<L_SEQ, 256, 0, stream>>>(x, pre_s, ws_hf, ws_hb);
  k_dtgemv<<<L_SEQ, 256, 0, stream>>>(ws_hf, W_in, ws_dtr);
  k_gemm_bf16<128, 128, 4, 4><<<dim3(NPADJ / 128, L_SEQ / 128), 256, 0, stream>>>(
      ws_hb, ws_W1h, ws_zx, DPROJ, DMODEL, DPROJ);
  k_dtscan<<<NHEADS, 256, 0, stream>>>(ws_dtr, dt_b, A_log, ws_hd, ws_cf, ws_cdt, ws_cD);
  k_rotate<<<L_SEQ, 256, 0, stream>>>(ws_zx, ws_cdt, omega, ws_Br, ws_Cr, ws_U);
  k_chunkX<<<dim3(NCHUNK, NHEADS), 256, 0, stream>>>(ws_Br, ws_U, ws_cD, ws_cf, ws_X);
  k_statepass<<<NHEADS * 8, 256, 0, stream>>>(ws_X, ws_cD, ws_Hs);
  k_yout_mfma<<<dim3(NCHUNK, NHEADS), 256, 0, stream>>>(ws_Br, ws_Cr, ws_U, ws_Hs, ws_cD, ws_cf, ws_hd, Dvec, ws_Y);
  k_cvtw<<<dim3(DMODEL / 32, DINNER / 32), 256, 0, stream>>>(W_out, ws_W2h, ws_W2l, DINNER, DMODEL, DMODEL);
  k_gate<<<L_SEQ, 256, 0, stream>>>(ws_Y, ws_zx, nw, ws_Gh, ws_Gl);
  k_gemm_bf16x3<64, 64, 2, 2><<<dim3(DMODEL / 64, L_SEQ / 64), 256, 0, stream>>>(
      ws_Gh, ws_Gl, ws_W2h, ws_W2l, ws_T, DMODEL, DINNER, DMODEL);
  k_final<<<L_SEQ, 256, 0, stream>>>(x, ws_T, post_s, out);
}

// Round 9
// 218.838 us; speedup vs baseline: 1.7019x; 1.1018x over previous
//
#include <hip/hip_runtime.h>
#include <cstdint>

#define L_SEQ   1024
#define DMODEL  768
#define DINNER  1536
#define NHEADS  24
#define HEADDIM 64
#define DSTATE  192
#define NPAIR   48
#define DPROJ   3480
#define NPADJ   3584      // DPROJ padded to 128 multiple for GEMM1
#define NCHUNK  16
#define QCH     64
#define EPSF    1e-6f

typedef __attribute__((ext_vector_type(8))) short short8;
typedef __attribute__((ext_vector_type(4))) float f32x4;

__device__ __forceinline__ unsigned short f2bf(float x) {
  union { float f; uint32_t u; } v; v.f = x;
  uint32_t r = (v.u + 0x7FFFu + ((v.u >> 16) & 1u)) >> 16;
  return (unsigned short)r;
}
__device__ __forceinline__ float bf2f(unsigned short b) {
  union { float f; uint32_t u; } v; v.u = ((uint32_t)b) << 16;
  return v.f;
}

__device__ __forceinline__ float blockReduceSum256(float v, float* red) {
#pragma unroll
  for (int m = 32; m; m >>= 1) v += __shfl_xor(v, m, 64);
  int wid = threadIdx.x >> 6, lane = threadIdx.x & 63;
  if (lane == 0) red[wid] = v;
  __syncthreads();
  float s = red[0] + red[1] + red[2] + red[3];
  __syncthreads();
  return s;
}

// ---------- K0: fp32 W[K][N] -> bf16 transposed [Npad][K] ----------
__global__ __launch_bounds__(256) void k_cvtw(const float* __restrict__ W,
                                              unsigned short* __restrict__ Wh,
                                              int K, int N, int Npad) {
  __shared__ float tile[32][33];
  int n0 = blockIdx.x * 32, k0 = blockIdx.y * 32;
  int tr = threadIdx.x >> 3, tc4 = (threadIdx.x & 7) << 2;
  const float* wp = W + (size_t)(k0 + tr) * N + n0 + tc4;
  float4 v = make_float4(0.f, 0.f, 0.f, 0.f);
  if (n0 + tc4 + 3 < N) {
    v = *(const float4*)wp;
  } else {
    if (n0 + tc4     < N) v.x = wp[0];
    if (n0 + tc4 + 1 < N) v.y = wp[1];
    if (n0 + tc4 + 2 < N) v.z = wp[2];
    if (n0 + tc4 + 3 < N) v.w = wp[3];
  }
  tile[tr][tc4 + 0] = v.x; tile[tr][tc4 + 1] = v.y;
  tile[tr][tc4 + 2] = v.z; tile[tr][tc4 + 3] = v.w;
  __syncthreads();
  ushort4 oh;
  oh.x = f2bf(tile[tc4 + 0][tr]);
  oh.y = f2bf(tile[tc4 + 1][tr]);
  oh.z = f2bf(tile[tc4 + 2][tr]);
  oh.w = f2bf(tile[tc4 + 3][tr]);
  *(ushort4*)&Wh[(size_t)(n0 + tr) * K + k0 + tc4] = oh;
}

// ---------- K1: fused pre-RMSNorm + fp32 dt GEMV (h row kept in LDS) ----------
__global__ __launch_bounds__(256) void k_prenorm_dt(const float* __restrict__ x,
                                                    const float* __restrict__ pre_scale,
                                                    const float* __restrict__ W_in,
                                                    unsigned short* __restrict__ hb,
                                                    float* __restrict__ dtr) {
  __shared__ float hs[DMODEL];
  __shared__ float red[4];
  __shared__ float part[NHEADS][8];
  int l = blockIdx.x, tid = threadIdx.x;
  const float* xr = x + (size_t)l * DMODEL;
  float v[3]; float ss = 0.f;
#pragma unroll
  for (int k = 0; k < 3; ++k) { v[k] = xr[tid + k * 256]; ss += v[k] * v[k]; }
  ss = blockReduceSum256(ss, red);
  float r = rsqrtf(ss * (1.f / DMODEL) + EPSF);
#pragma unroll
  for (int k = 0; k < 3; ++k) {
    int i = tid + k * 256;
    float hv = v[k] * r * (1.f + pre_scale[i]);
    hs[i] = hv;
    hb[(size_t)l * DMODEL + i] = f2bf(hv);
  }
  __syncthreads();
  if (tid < 192) {
    int hh = tid >> 3, seg = tid & 7;
    float s = 0.f;
    int k0 = seg * 96;
#pragma unroll 4
    for (int k = k0; k < k0 + 96; ++k)
      s = fmaf(hs[k], W_in[(size_t)k * DPROJ + 3456 + hh], s);
    part[hh][seg] = s;
  }
  __syncthreads();
  if (tid < NHEADS) {
    float s = 0.f;
#pragma unroll
    for (int q = 0; q < 8; ++q) s += part[tid][q];
    dtr[(size_t)l * NHEADS + tid] = s;
  }
}

// ---------- K2/K9: plain bf16 MFMA GEMM ----------
template<int BM, int BN, int TM, int TN>
__global__ __launch_bounds__(256) void k_gemm_bf16(
    const unsigned short* __restrict__ A,
    const unsigned short* __restrict__ Bt,
    float* __restrict__ C,
    int N, int K, int ldc) {
  __shared__ unsigned short As[BM * 32];
  __shared__ unsigned short Bs[BN * 32];
  const int tid = threadIdx.x;
  const int lane = tid & 63, w = tid >> 6;
  const int wm = (w >> 1) * (TM * 16), wn = (w & 1) * (TN * 16);
  const int bm = blockIdx.y * BM, bn = blockIdx.x * BN;
  const int r15 = lane & 15, kg = lane >> 4;
  f32x4 acc[TM][TN] = {};
  for (int k0 = 0; k0 < K; k0 += 32) {
    __syncthreads();
#pragma unroll
    for (int ch = tid; ch < BM * 4; ch += 256) {
      int r = ch >> 2, kq = (ch & 3) << 3;
      *(short8*)&As[r * 32 + kq] = *(const short8*)&A[(size_t)(bm + r) * K + k0 + kq];
    }
#pragma unroll
    for (int ch = tid; ch < BN * 4; ch += 256) {
      int r = ch >> 2, kq = (ch & 3) << 3;
      *(short8*)&Bs[r * 32 + kq] = *(const short8*)&Bt[(size_t)(bn + r) * K + k0 + kq];
    }
    __syncthreads();
    short8 af[TM], bfr[TN];
#pragma unroll
    for (int i = 0; i < TM; ++i)
      af[i] = *(const short8*)&As[(wm + i * 16 + r15) * 32 + kg * 8];
#pragma unroll
    for (int j = 0; j < TN; ++j)
      bfr[j] = *(const short8*)&Bs[(wn + j * 16 + r15) * 32 + kg * 8];
#pragma unroll
    for (int i = 0; i < TM; ++i)
#pragma unroll
      for (int j = 0; j < TN; ++j)
        acc[i][j] = __builtin_amdgcn_mfma_f32_16x16x32_bf16(af[i], bfr[j], acc[i][j], 0, 0, 0);
  }
  const int crow = bm + wm + (lane >> 4) * 4;
  const int ccol = bn + wn + r15;
#pragma unroll
  for (int i = 0; i < TM; ++i)
#pragma unroll
    for (int j = 0; j < TN; ++j) {
      int col = ccol + j * 16;
      if (col < N) {
        float* cp = C + (size_t)(crow + i * 16) * ldc + col;
#pragma unroll
        for (int r = 0; r < 4; ++r) cp[(size_t)r * ldc] = acc[i][j][r];
      }
    }
}

// ---------- K3: dt softplus + cumsum, shuffle scan ----------
__global__ __launch_bounds__(256) void k_dtscan(const float* __restrict__ dtr,
                                                const float* __restrict__ dt_bias,
                                                const float* __restrict__ A_log,
                                                float* __restrict__ halfdt,
                                                float* __restrict__ cfac,
                                                float* __restrict__ cumdt,
                                                float* __restrict__ cumD) {
  __shared__ float sdt[L_SEQ];
  __shared__ float wsum[4];
  int hh = blockIdx.x, tid = threadIdx.x;
  int lane = tid & 63, wid = tid >> 6;
  float bias = dt_bias[hh];
  float Ah = -(expf(A_log[hh]) + 1e-4f);
  int l0 = tid * 4;
  float d[4], e[4];
#pragma unroll
  for (int k = 0; k < 4; ++k) {
    float draw = dtr[(size_t)(l0 + k) * NHEADS + hh] + bias;
    d[k] = (draw > 20.f) ? draw : log1pf(expf(draw));
    sdt[l0 + k] = d[k];
  }
  e[0] = d[0]; e[1] = e[0] + d[1]; e[2] = e[1] + d[2]; e[3] = e[2] + d[3];
  float tot = e[3];
  float s = tot;
#pragma unroll
  for (int off = 1; off < 64; off <<= 1) {
    float n = __shfl_up(s, off, 64);
    if (lane >= off) s += n;
  }
  if (lane == 63) wsum[wid] = s;
  __syncthreads();
  float woff = 0.f;
#pragma unroll
  for (int q = 0; q < 4; ++q) woff += (q < wid) ? wsum[q] : 0.f;
  float excl = woff + s - tot;
  float cd0 = excl + e[0], cd1 = excl + e[1], cd2 = excl + e[2], cd3 = excl + e[3];
  float dnext3 = (l0 + 3 < L_SEQ - 1) ? sdt[l0 + 4] : 0.f;
  float4 o_hd = make_float4(0.5f * d[0], 0.5f * d[1], 0.5f * d[2], 0.5f * d[3]);
  float4 o_cf = make_float4(0.5f * (d[0] + d[1]), 0.5f * (d[1] + d[2]),
                            0.5f * (d[2] + d[3]), 0.5f * (d[3] + dnext3));
  float4 o_cd = make_float4(cd0, cd1, cd2, cd3);
  float4 o_cD = make_float4(Ah * cd0, Ah * cd1, Ah * cd2, Ah * cd3);
  size_t idx = (size_t)hh * L_SEQ + l0;
  *(float4*)&halfdt[idx] = o_hd;
  *(float4*)&cfac[idx]   = o_cf;
  *(float4*)&cumdt[idx]  = o_cd;
  *(float4*)&cumD[idx]   = o_cD;
}

// ---------- K4: rotate B/C per head (bf16 out) + gather U contiguous ----------
__global__ __launch_bounds__(256) void k_rotate(const float* __restrict__ zx,
                                                const float* __restrict__ cumdt,
                                                const float* __restrict__ omega,
                                                unsigned short* __restrict__ Brot,
                                                unsigned short* __restrict__ Crot,
                                                float* __restrict__ U) {
  int l = blockIdx.x, tid = threadIdx.x;
  const float* row = zx + (size_t)l * DPROJ;
  for (int i = tid; i < 384; i += 256) {
    float4 v = *(const float4*)(row + 1536 + i * 4);
    int hh = i >> 4;
    int p = (i & 15) << 2;
    *(float4*)&U[((size_t)(hh * L_SEQ + l)) * HEADDIM + p] = v;
  }
  for (int i = tid; i < NHEADS * 96; i += 256) {
    int hh = i / 96, j = i - hh * 96;
    int n = 2 * j;
    float b0 = row[3072 + n], b1 = row[3072 + n + 1];
    float c0 = row[3264 + n], c1 = row[3264 + n + 1];
    size_t base = ((size_t)(hh * L_SEQ + l)) * DSTATE + n;
    float br0 = b0, br1 = b1, cr0 = c0, cr1 = c1;
    if (j < NPAIR) {
      float ph = cumdt[hh * L_SEQ + l] * omega[hh * NPAIR + j];
      float sp, cp;
      sincosf(ph, &sp, &cp);
      br0 =  b0 * cp + b1 * sp;
      br1 = -b0 * sp + b1 * cp;
      cr0 =  c0 * cp - c1 * sp;
      cr1 =  c0 * sp + c1 * cp;
    }
    ushort2 bo, co;
    bo.x = f2bf(br0); bo.y = f2bf(br1);
    co.x = f2bf(cr0); co.y = f2bf(cr1);
    *(ushort2*)&Brot[base] = bo;
    *(ushort2*)&Crot[base] = co;
  }
}

// ---------- K5: per-(head,chunk) state contribution X_c[p][n] ----------
__global__ __launch_bounds__(256) void k_chunkX(const unsigned short* __restrict__ Brot,
                                                const float* __restrict__ U,
                                                const float* __restrict__ cumD,
                                                const float* __restrict__ cfac,
                                                float* __restrict__ X) {
  const int c = blockIdx.x, hh = blockIdx.y;
  const int tid = threadIdx.x;
  const size_t hl = (size_t)hh * L_SEQ;
  const int l0 = c * QCH;
  __shared__ float Bs[QCH][DSTATE];
  __shared__ float su[QCH][HEADDIM];
  for (int i = tid; i < QCH * 48; i += 256) {
    int m = i / 48, q = i - m * 48;
    ushort4 bv = *(const ushort4*)&Brot[(hl + l0 + m) * DSTATE + (q << 2)];
    Bs[m][(q << 2) + 0] = bf2f(bv.x);
    Bs[m][(q << 2) + 1] = bf2f(bv.y);
    Bs[m][(q << 2) + 2] = bf2f(bv.z);
    Bs[m][(q << 2) + 3] = bf2f(bv.w);
  }
  float dlast = cumD[hl + l0 + QCH - 1];
  for (int i = tid; i < QCH * 16; i += 256) {
    int m = i >> 4, q = i & 15;
    float s = expf(dlast - cumD[hl + l0 + m]) * cfac[hl + l0 + m];
    float4 v = *(const float4*)&U[(hl + l0 + m) * HEADDIM + (q << 2)];
    v.x *= s; v.y *= s; v.z *= s; v.w *= s;
    *(float4*)&su[m][q << 2] = v;
  }
  __syncthreads();
  const int ngrp = tid & 15, pgrp = tid >> 4;
  const int n0 = ngrp * 12, p0 = pgrp << 2;
  float acc[12][4] = {};
  for (int m = 0; m < QCH; ++m) {
    const float4 uv = *(const float4*)&su[m][p0];
    const float4 b0 = *(const float4*)&Bs[m][n0];
    const float4 b1 = *(const float4*)&Bs[m][n0 + 4];
    const float4 b2 = *(const float4*)&Bs[m][n0 + 8];
    float u4[4] = {uv.x, uv.y, uv.z, uv.w};
    float bb[12] = {b0.x, b0.y, b0.z, b0.w, b1.x, b1.y, b1.z, b1.w, b2.x, b2.y, b2.z, b2.w};
#pragma unroll
    for (int j = 0; j < 12; ++j)
#pragma unroll
      for (int i = 0; i < 4; ++i) acc[j][i] = fmaf(bb[j], u4[i], acc[j][i]);
  }
  const size_t obase = ((size_t)(hh * NCHUNK + c)) * (HEADDIM * DSTATE);
#pragma unroll
  for (int i = 0; i < 4; ++i)
#pragma unroll
    for (int j4 = 0; j4 < 3; ++j4)
      *(float4*)&X[obase + (size_t)(p0 + i) * DSTATE + n0 + j4 * 4] =
          make_float4(acc[j4 * 4 + 0][i], acc[j4 * 4 + 1][i], acc[j4 * 4 + 2][i], acc[j4 * 4 + 3][i]);
}

// ---------- K6: sequential chunk-state pass (Hs out as bf16) ----------
__global__ __launch_bounds__(256) void k_statepass(const float* __restrict__ X,
                                                   const float* __restrict__ cumD,
                                                   unsigned short* __restrict__ Hs) {
  int hh = blockIdx.x >> 3, part = blockIdx.x & 7;
  int tid = threadIdx.x;
  const size_t hl = (size_t)hh * L_SEQ;
  float Hc[6] = {0.f, 0.f, 0.f, 0.f, 0.f, 0.f};
  for (int c = 0; c < NCHUNK; ++c) {
    float r = 1.f;
    if (c > 0) r = expf(cumD[hl + c * QCH + QCH - 1] - cumD[hl + c * QCH - 1]);
    size_t base = ((size_t)(hh * NCHUNK + c)) * (HEADDIM * DSTATE) + part * 1536 + tid;
#pragma unroll
    for (int k = 0; k < 6; ++k) {
      Hs[base + k * 256] = f2bf(Hc[k]);
      Hc[k] = fmaf(r, Hc[k], X[base + k * 256]);
    }
  }
}

// ---------- K7: per-(head,chunk) output Y via MFMA ----------
#define YP 104   // bf16 pad stride for 96-col K tiles
#define SP 72    // bf16 pad stride for 64-col tiles
__global__ __launch_bounds__(256) void k_yout_mfma(
    const unsigned short* __restrict__ Brot, const unsigned short* __restrict__ Crot,
    const float* __restrict__ U,             const unsigned short* __restrict__ Hs,
    const float* __restrict__ cumD, const float* __restrict__ cfac,
    const float* __restrict__ halfdt, const float* __restrict__ Dvec,
    float* __restrict__ Yout) {
  const int c = blockIdx.x, hh = blockIdx.y;
  const int tid = threadIdx.x;
  const int lane = tid & 63, w = tid >> 6;
  const int wr = w >> 1, wc = w & 1;
  const int r15 = lane & 15, kg = lane >> 4;
  const int l0 = c * QCH;
  const size_t hl = (size_t)hh * L_SEQ;

  __shared__ unsigned short Cs[64][YP];
  __shared__ unsigned short Bs[64][YP];   // reused for Hs tiles in Z phase
  __shared__ unsigned short Ss[64][SP];
  __shared__ unsigned short Ut[64][SP];
  __shared__ float Dc[64], cfs[64], hds[64];

  if (tid < 64) {
    Dc[tid]  = cumD[hl + l0 + tid];
    cfs[tid] = cfac[hl + l0 + tid];
    hds[tid] = halfdt[hl + l0 + tid];
  }
  // stage U transposed -> Ut[p][m]
  for (int idx = tid; idx < 64 * 64; idx += 256) {
    int m = idx >> 6, p = idx & 63;
    Ut[p][m] = f2bf(U[(hl + l0 + m) * HEADDIM + p]);
  }

  // Phase A: S = C · B^T over K=192 in two halves of 96 (raw ushort copies)
  f32x4 accS[2][2] = {};
  for (int half = 0; half < 2; ++half) {
    __syncthreads();
    for (int idx = tid; idx < 64 * 12; idx += 256) {
      int t = idx / 12, q = (idx % 12) << 3;
      *(short8*)&Cs[t][q] = *(const short8*)&Crot[(hl + l0 + t) * DSTATE + 96 * half + q];
      *(short8*)&Bs[t][q] = *(const short8*)&Brot[(hl + l0 + t) * DSTATE + 96 * half + q];
    }
    __syncthreads();
#pragma unroll
    for (int kk = 0; kk < 3; ++kk) {
      short8 af[2], bfr[2];
#pragma unroll
      for (int i = 0; i < 2; ++i)
        af[i] = *(const short8*)&Cs[wr * 32 + i * 16 + r15][kk * 32 + kg * 8];
#pragma unroll
      for (int j = 0; j < 2; ++j)
        bfr[j] = *(const short8*)&Bs[wc * 32 + j * 16 + r15][kk * 32 + kg * 8];
#pragma unroll
      for (int i = 0; i < 2; ++i)
#pragma unroll
        for (int j = 0; j < 2; ++j)
          accS[i][j] = __builtin_amdgcn_mfma_f32_16x16x32_bf16(af[i], bfr[j], accS[i][j], 0, 0, 0);
    }
  }
  // apply causal trapezoid weights in fp32, write Sw to LDS as bf16
#pragma unroll
  for (int i = 0; i < 2; ++i)
#pragma unroll
    for (int j = 0; j < 2; ++j)
#pragma unroll
      for (int r = 0; r < 4; ++r) {
        int t = wr * 32 + i * 16 + kg * 4 + r;
        int m = wc * 32 + j * 16 + r15;
        float wgt = 0.f;
        if (m < t)       wgt = __expf(Dc[t] - Dc[m]) * cfs[m];
        else if (m == t) wgt = hds[t];
        Ss[t][m] = f2bf(accS[i][j][r] * wgt);
      }

  // Phase B: Z = C · Hs^T over K=192 in two halves (Bs <- Hs bf16 rows = p)
  f32x4 accZ[2][2] = {};
  const size_t hcb = ((size_t)(hh * NCHUNK + c)) * (HEADDIM * DSTATE);
  for (int half = 0; half < 2; ++half) {
    __syncthreads();
    for (int idx = tid; idx < 64 * 12; idx += 256) {
      int t = idx / 12, q = (idx % 12) << 3;
      *(short8*)&Cs[t][q] = *(const short8*)&Crot[(hl + l0 + t) * DSTATE + 96 * half + q];
      *(short8*)&Bs[t][q] = *(const short8*)&Hs[hcb + (size_t)t * DSTATE + 96 * half + q];
    }
    __syncthreads();
#pragma unroll
    for (int kk = 0; kk < 3; ++kk) {
      short8 af[2], bfr[2];
#pragma unroll
      for (int i = 0; i < 2; ++i)
        af[i] = *(const short8*)&Cs[wr * 32 + i * 16 + r15][kk * 32 + kg * 8];
#pragma unroll
      for (int j = 0; j < 2; ++j)
        bfr[j] = *(const short8*)&Bs[wc * 32 + j * 16 + r15][kk * 32 + kg * 8];
#pragma unroll
      for (int i = 0; i < 2; ++i)
#pragma unroll
        for (int j = 0; j < 2; ++j)
          accZ[i][j] = __builtin_amdgcn_mfma_f32_16x16x32_bf16(af[i], bfr[j], accZ[i][j], 0, 0, 0);
    }
  }

  // Phase C: Y1 = Sw · Ut^T (K = 64)
  f32x4 accY[2][2] = {};
#pragma unroll
  for (int kk = 0; kk < 2; ++kk) {
    short8 af[2], bfr[2];
#pragma unroll
    for (int i = 0; i < 2; ++i)
      af[i] = *(const short8*)&Ss[wr * 32 + i * 16 + r15][kk * 32 + kg * 8];
#pragma unroll
    for (int j = 0; j < 2; ++j)
      bfr[j] = *(const short8*)&Ut[wc * 32 + j * 16 + r15][kk * 32 + kg * 8];
#pragma unroll
    for (int i = 0; i < 2; ++i)
#pragma unroll
      for (int j = 0; j < 2; ++j)
        accY[i][j] = __builtin_amdgcn_mfma_f32_16x16x32_bf16(af[i], bfr[j], accY[i][j], 0, 0, 0);
  }

  // Epilogue
  float Dbase = (c > 0) ? cumD[hl + l0 - 1] : 0.f;
  float Dh = Dvec[hh];
#pragma unroll
  for (int i = 0; i < 2; ++i)
#pragma unroll
    for (int r = 0; r < 4; ++r) {
      int t = wr * 32 + i * 16 + kg * 4 + r;
      float et = __expf(Dc[t] - Dbase);
#pragma unroll
      for (int j = 0; j < 2; ++j) {
        int p = wc * 32 + j * 16 + r15;
        float u = U[(hl + l0 + t) * HEADDIM + p];
        Yout[(size_t)(l0 + t) * DINNER + hh * HEADDIM + p] =
            accY[i][j][r] + et * accZ[i][j][r] + Dh * u;
      }
    }
}

// ---------- K8: gate (silu) + RMSNorm over 1536 -> bf16 ----------
__global__ __launch_bounds__(256) void k_gate(const float* __restrict__ Y,
                                              const float* __restrict__ zx,
                                              const float* __restrict__ nw,
                                              unsigned short* __restrict__ Gh) {
  __shared__ float gbuf[DINNER];
  __shared__ float red[4];
  int l = blockIdx.x, tid = threadIdx.x;
  float ss = 0.f;
  for (int i = tid; i < DINNER; i += 256) {
    float y = Y[(size_t)l * DINNER + i];
    float z = zx[(size_t)l * DPROJ + i];
    float g = y * z / (1.f + expf(-z));
    gbuf[i] = g;
    ss += g * g;
  }
  ss = blockReduceSum256(ss, red);
  float r = rsqrtf(ss * (1.f / DINNER) + EPSF);
  for (int i = tid; i < DINNER; i += 256)
    Gh[(size_t)l * DINNER + i] = f2bf(gbuf[i] * r * nw[i]);
}

// ---------- K10: final RMSNorm + residual ----------
__global__ __launch_bounds__(256) void k_final(const float* __restrict__ x,
                                               const float* __restrict__ T,
                                               const float* __restrict__ post_scale,
                                               float* __restrict__ out) {
  __shared__ float red[4];
  int l = blockIdx.x, tid = threadIdx.x;
  const float* tr = T + (size_t)l * DMODEL;
  float v[3]; float ss = 0.f;
#pragma unroll
  for (int k = 0; k < 3; ++k) { v[k] = tr[tid + k * 256]; ss += v[k] * v[k]; }
  ss = blockReduceSum256(ss, red);
  float r = rsqrtf(ss * (1.f / DMODEL) + EPSF);
#pragma unroll
  for (int k = 0; k < 3; ++k) {
    int i = tid + k * 256;
    out[(size_t)l * DMODEL + i] = x[(size_t)l * DMODEL + i] + v[k] * r * (1.f + post_scale[i]);
  }
}

// ---------- launcher ----------
extern "C" void kernel_launch(void* const* d_in, const int* in_sizes, int n_in,
                              void* d_out, int out_size, void* d_ws, size_t ws_size,
                              hipStream_t stream) {
  const float* x      = (const float*)d_in[0];
  const float* pre_s  = (const float*)d_in[1];
  const float* W_in   = (const float*)d_in[2];
  const float* dt_b   = (const float*)d_in[3];
  const float* A_log  = (const float*)d_in[4];
  const float* omega  = (const float*)d_in[5];
  const float* Dvec   = (const float*)d_in[6];
  const float* nw     = (const float*)d_in[7];
  const float* W_out  = (const float*)d_in[8];
  const float* post_s = (const float*)d_in[9];
  float* out = (float*)d_out;

  float* ws = (float*)d_ws;
  size_t off = 0;
  auto nxt = [&](size_t n) { float* p = ws + off; off += (n + 3) & ~(size_t)3; return p; };
  float* ws_zx  = nxt((size_t)L_SEQ * DPROJ);
  unsigned short* ws_hb = (unsigned short*)nxt((size_t)L_SEQ * DMODEL / 2);
  float* ws_dtr = nxt((size_t)L_SEQ * NHEADS);
  float* ws_hd  = nxt((size_t)NHEADS * L_SEQ);
  float* ws_cf  = nxt((size_t)NHEADS * L_SEQ);
  float* ws_cdt = nxt((size_t)NHEADS * L_SEQ);
  float* ws_cD  = nxt((size_t)NHEADS * L_SEQ);
  unsigned short* ws_Brb = (unsigned short*)nxt((size_t)NHEADS * L_SEQ * DSTATE / 2);
  unsigned short* ws_Crb = (unsigned short*)nxt((size_t)NHEADS * L_SEQ * DSTATE / 2);
  float* ws_U   = nxt((size_t)NHEADS * L_SEQ * HEADDIM);
  float* ws_X   = nxt((size_t)NHEADS * NCHUNK * HEADDIM * DSTATE);
  unsigned short* ws_Hsb = (unsigned short*)nxt((size_t)NHEADS * NCHUNK * HEADDIM * DSTATE / 2);
  float* ws_Y   = nxt((size_t)L_SEQ * DINNER);
  unsigned short* ws_Gh = (unsigned short*)nxt((size_t)L_SEQ * DINNER / 2);
  // aliases (lifetimes disjoint, same-stream serialization):
  unsigned short* ws_W1h = (unsigned short*)ws_X;   // NPADJ*768 ushorts (2.75M) < X (4.7M floats); dead before chunkX
  unsigned short* ws_W2h = ws_Brb;                  // 768*1536 ushorts (1.18M) < Brb (4.7M ushorts); Br dead after yout
  float* ws_T = ws_X;                               // GEMM2 out; X dead after statepass

  k_cvtw<<<dim3(NPADJ / 32, DMODEL / 32), 256, 0, stream>>>(W_in, ws_W1h, DMODEL, DPROJ, NPADJ);
  k_prenorm_dt<<<L_SEQ, 256, 0, stream>>>(x, pre_s, W_in, ws_hb, ws_dtr);
  k_gemm_bf16<128, 128, 4, 4><<<dim3(NPADJ / 128, L_SEQ / 128), 256, 0, stream>>>(
      ws_hb, ws_W1h, ws_zx, DPROJ, DMODEL, DPROJ);
  k_dtscan<<<NHEADS, 256, 0, stream>>>(ws_dtr, dt_b, A_log, ws_hd, ws_cf, ws_cdt, ws_cD);
  k_rotate<<<L_SEQ, 256, 0, stream>>>(ws_zx, ws_cdt, omega, ws_Brb, ws_Crb, ws_U);
  k_chunkX<<<dim3(NCHUNK, NHEADS), 256, 0, stream>>>(ws_Brb, ws_U, ws_cD, ws_cf, ws_X);
  k_statepass<<<NHEADS * 8, 256, 0, stream>>>(ws_X, ws_cD, ws_Hsb);
  k_yout_mfma<<<dim3(NCHUNK, NHEADS), 256, 0, stream>>>(ws_Brb, ws_Crb, ws_U, ws_Hsb, ws_cD, ws_cf, ws_hd, Dvec, ws_Y);
  k_cvtw<<<dim3(DMODEL / 32, DINNER / 32), 256, 0, stream>>>(W_out, ws_W2h, DINNER, DMODEL, DMODEL);
  k_gate<<<L_SEQ, 256, 0, stream>>>(ws_Y, ws_zx, nw, ws_Gh);
  k_gemm_bf16<64, 64, 2, 2><<<dim3(DMODEL / 64, L_SEQ / 64), 256, 0, stream>>>(
      ws_Gh, ws_W2h, ws_T, DMODEL, DINNER, DMODEL);
  k_final<<<L_SEQ, 256, 0, stream>>>(x, ws_T, post_s, out);
}

// Round 10
// 199.038 us; speedup vs baseline: 1.8712x; 1.0995x over previous
//
#include <hip/hip_runtime.h>
#include <cstdint>

#define L_SEQ   1024
#define DMODEL  768
#define DINNER  1536
#define NHEADS  24
#define HEADDIM 64
#define DSTATE  192
#define NPAIR   48
#define DPROJ   3480
#define NPADJ   3584      // DPROJ padded to 128 multiple for GEMM1
#define NCHUNK  16
#define QCH     64
#define EPSF    1e-6f

typedef __attribute__((ext_vector_type(8))) short short8;
typedef __attribute__((ext_vector_type(4))) float f32x4;

__device__ __forceinline__ unsigned short f2bf(float x) {
  union { float f; uint32_t u; } v; v.f = x;
  uint32_t r = (v.u + 0x7FFFu + ((v.u >> 16) & 1u)) >> 16;
  return (unsigned short)r;
}
__device__ __forceinline__ float bf2f(unsigned short b) {
  union { float f; uint32_t u; } v; v.u = ((uint32_t)b) << 16;
  return v.f;
}

__device__ __forceinline__ float blockReduceSum256(float v, float* red) {
#pragma unroll
  for (int m = 32; m; m >>= 1) v += __shfl_xor(v, m, 64);
  int wid = threadIdx.x >> 6, lane = threadIdx.x & 63;
  if (lane == 0) red[wid] = v;
  __syncthreads();
  float s = red[0] + red[1] + red[2] + red[3];
  __syncthreads();
  return s;
}

// ---------- K0: both weights fp32 [K][N] -> bf16 transposed [Npad][K], one launch ----------
__global__ __launch_bounds__(256) void k_cvtw2(const float* __restrict__ Wa,
                                               unsigned short* __restrict__ Wha,
                                               const float* __restrict__ Wb,
                                               unsigned short* __restrict__ Whb) {
  __shared__ float tile[32][33];
  int b = blockIdx.x;
  const float* W; unsigned short* Wt; int K, N, bx, by;
  if (b < 112 * 24) {            // W_in: [768][3480] -> [3584][768]
    W = Wa; Wt = Wha; K = DMODEL; N = DPROJ; bx = b % 112; by = b / 112;
  } else {                       // W_out: [1536][768] -> [768][1536]
    b -= 112 * 24;
    W = Wb; Wt = Whb; K = DINNER; N = DMODEL; bx = b % 24; by = b / 24;
  }
  int n0 = bx * 32, k0 = by * 32;
  int tr = threadIdx.x >> 3, tc4 = (threadIdx.x & 7) << 2;
  const float* wp = W + (size_t)(k0 + tr) * N + n0 + tc4;
  float4 v = make_float4(0.f, 0.f, 0.f, 0.f);
  if (n0 + tc4 + 3 < N) {
    v = *(const float4*)wp;
  } else {
    if (n0 + tc4     < N) v.x = wp[0];
    if (n0 + tc4 + 1 < N) v.y = wp[1];
    if (n0 + tc4 + 2 < N) v.z = wp[2];
    if (n0 + tc4 + 3 < N) v.w = wp[3];
  }
  tile[tr][tc4 + 0] = v.x; tile[tr][tc4 + 1] = v.y;
  tile[tr][tc4 + 2] = v.z; tile[tr][tc4 + 3] = v.w;
  __syncthreads();
  ushort4 oh;
  oh.x = f2bf(tile[tc4 + 0][tr]);
  oh.y = f2bf(tile[tc4 + 1][tr]);
  oh.z = f2bf(tile[tc4 + 2][tr]);
  oh.w = f2bf(tile[tc4 + 3][tr]);
  *(ushort4*)&Wt[(size_t)(n0 + tr) * K + k0 + tc4] = oh;
}

// ---------- K1: fused pre-RMSNorm + fp32 dt GEMV ----------
__global__ __launch_bounds__(256) void k_prenorm_dt(const float* __restrict__ x,
                                                    const float* __restrict__ pre_scale,
                                                    const float* __restrict__ W_in,
                                                    unsigned short* __restrict__ hb,
                                                    float* __restrict__ dtr) {
  __shared__ float hs[DMODEL];
  __shared__ float red[4];
  __shared__ float part[NHEADS][8];
  int l = blockIdx.x, tid = threadIdx.x;
  const float* xr = x + (size_t)l * DMODEL;
  float v[3]; float ss = 0.f;
#pragma unroll
  for (int k = 0; k < 3; ++k) { v[k] = xr[tid + k * 256]; ss += v[k] * v[k]; }
  ss = blockReduceSum256(ss, red);
  float r = rsqrtf(ss * (1.f / DMODEL) + EPSF);
#pragma unroll
  for (int k = 0; k < 3; ++k) {
    int i = tid + k * 256;
    float hv = v[k] * r * (1.f + pre_scale[i]);
    hs[i] = hv;
    hb[(size_t)l * DMODEL + i] = f2bf(hv);
  }
  __syncthreads();
  if (tid < 192) {
    int hh = tid >> 3, seg = tid & 7;
    float s = 0.f;
    int k0 = seg * 96;
#pragma unroll 4
    for (int k = k0; k < k0 + 96; ++k)
      s = fmaf(hs[k], W_in[(size_t)k * DPROJ + 3456 + hh], s);
    part[hh][seg] = s;
  }
  __syncthreads();
  if (tid < NHEADS) {
    float s = 0.f;
#pragma unroll
    for (int q = 0; q < 8; ++q) s += part[tid][q];
    dtr[(size_t)l * NHEADS + tid] = s;
  }
}

// ---------- K2/K9: bf16 MFMA GEMM with reg-staged double buffer ----------
template<int BM, int BN, int TM, int TN>
__global__ __launch_bounds__(256) void k_gemm_bf16(
    const unsigned short* __restrict__ A,
    const unsigned short* __restrict__ Bt,
    float* __restrict__ C,
    int N, int K, int ldc) {
  constexpr int AC = (BM * 4) / 256;   // short8 chunks per thread for A tile
  constexpr int BC = (BN * 4) / 256;
  __shared__ unsigned short As[BM * 32];
  __shared__ unsigned short Bs[BN * 32];
  const int tid = threadIdx.x;
  const int lane = tid & 63, w = tid >> 6;
  const int wm = (w >> 1) * (TM * 16), wn = (w & 1) * (TN * 16);
  const int bm = blockIdx.y * BM, bn = blockIdx.x * BN;
  const int r15 = lane & 15, kg = lane >> 4;
  short8 ra[AC], rb[BC];
  auto loadG = [&](int k0) {
#pragma unroll
    for (int a = 0; a < AC; ++a) {
      int idx = tid + a * 256; int r = idx >> 2, kq = (idx & 3) << 3;
      ra[a] = *(const short8*)&A[(size_t)(bm + r) * K + k0 + kq];
    }
#pragma unroll
    for (int b = 0; b < BC; ++b) {
      int idx = tid + b * 256; int r = idx >> 2, kq = (idx & 3) << 3;
      rb[b] = *(const short8*)&Bt[(size_t)(bn + r) * K + k0 + kq];
    }
  };
  f32x4 acc[TM][TN] = {};
  loadG(0);
  for (int k0 = 0; k0 < K; k0 += 32) {
#pragma unroll
    for (int a = 0; a < AC; ++a) {
      int idx = tid + a * 256; int r = idx >> 2, kq = (idx & 3) << 3;
      *(short8*)&As[r * 32 + kq] = ra[a];
    }
#pragma unroll
    for (int b = 0; b < BC; ++b) {
      int idx = tid + b * 256; int r = idx >> 2, kq = (idx & 3) << 3;
      *(short8*)&Bs[r * 32 + kq] = rb[b];
    }
    __syncthreads();
    if (k0 + 32 < K) loadG(k0 + 32);   // next tile in flight under MFMA
    short8 af[TM], bfr[TN];
#pragma unroll
    for (int i = 0; i < TM; ++i)
      af[i] = *(const short8*)&As[(wm + i * 16 + r15) * 32 + kg * 8];
#pragma unroll
    for (int j = 0; j < TN; ++j)
      bfr[j] = *(const short8*)&Bs[(wn + j * 16 + r15) * 32 + kg * 8];
#pragma unroll
    for (int i = 0; i < TM; ++i)
#pragma unroll
      for (int j = 0; j < TN; ++j)
        acc[i][j] = __builtin_amdgcn_mfma_f32_16x16x32_bf16(af[i], bfr[j], acc[i][j], 0, 0, 0);
    __syncthreads();
  }
  const int crow = bm + wm + (lane >> 4) * 4;
  const int ccol = bn + wn + r15;
#pragma unroll
  for (int i = 0; i < TM; ++i)
#pragma unroll
    for (int j = 0; j < TN; ++j) {
      int col = ccol + j * 16;
      if (col < N) {
        float* cp = C + (size_t)(crow + i * 16) * ldc + col;
#pragma unroll
        for (int r = 0; r < 4; ++r) cp[(size_t)r * ldc] = acc[i][j][r];
      }
    }
}

// ---------- K3: dt softplus + cumsum, shuffle scan ----------
__global__ __launch_bounds__(256) void k_dtscan(const float* __restrict__ dtr,
                                                const float* __restrict__ dt_bias,
                                                const float* __restrict__ A_log,
                                                float* __restrict__ halfdt,
                                                float* __restrict__ cfac,
                                                float* __restrict__ cumdt,
                                                float* __restrict__ cumD) {
  __shared__ float sdt[L_SEQ];
  __shared__ float wsum[4];
  int hh = blockIdx.x, tid = threadIdx.x;
  int lane = tid & 63, wid = tid >> 6;
  float bias = dt_bias[hh];
  float Ah = -(expf(A_log[hh]) + 1e-4f);
  int l0 = tid * 4;
  float d[4], e[4];
#pragma unroll
  for (int k = 0; k < 4; ++k) {
    float draw = dtr[(size_t)(l0 + k) * NHEADS + hh] + bias;
    d[k] = (draw > 20.f) ? draw : log1pf(expf(draw));
    sdt[l0 + k] = d[k];
  }
  e[0] = d[0]; e[1] = e[0] + d[1]; e[2] = e[1] + d[2]; e[3] = e[2] + d[3];
  float tot = e[3];
  float s = tot;
#pragma unroll
  for (int off = 1; off < 64; off <<= 1) {
    float n = __shfl_up(s, off, 64);
    if (lane >= off) s += n;
  }
  if (lane == 63) wsum[wid] = s;
  __syncthreads();
  float woff = 0.f;
#pragma unroll
  for (int q = 0; q < 4; ++q) woff += (q < wid) ? wsum[q] : 0.f;
  float excl = woff + s - tot;
  float cd0 = excl + e[0], cd1 = excl + e[1], cd2 = excl + e[2], cd3 = excl + e[3];
  float dnext3 = (l0 + 3 < L_SEQ - 1) ? sdt[l0 + 4] : 0.f;
  float4 o_hd = make_float4(0.5f * d[0], 0.5f * d[1], 0.5f * d[2], 0.5f * d[3]);
  float4 o_cf = make_float4(0.5f * (d[0] + d[1]), 0.5f * (d[1] + d[2]),
                            0.5f * (d[2] + d[3]), 0.5f * (d[3] + dnext3));
  float4 o_cd = make_float4(cd0, cd1, cd2, cd3);
  float4 o_cD = make_float4(Ah * cd0, Ah * cd1, Ah * cd2, Ah * cd3);
  size_t idx = (size_t)hh * L_SEQ + l0;
  *(float4*)&halfdt[idx] = o_hd;
  *(float4*)&cfac[idx]   = o_cf;
  *(float4*)&cumdt[idx]  = o_cd;
  *(float4*)&cumD[idx]   = o_cD;
}

// ---------- K4: rotate B/C per head (bf16) + gather U contiguous (bf16) ----------
__global__ __launch_bounds__(256) void k_rotate(const float* __restrict__ zx,
                                                const float* __restrict__ cumdt,
                                                const float* __restrict__ omega,
                                                unsigned short* __restrict__ Brot,
                                                unsigned short* __restrict__ Crot,
                                                unsigned short* __restrict__ Ub) {
  int l = blockIdx.x, tid = threadIdx.x;
  const float* row = zx + (size_t)l * DPROJ;
  for (int i = tid; i < 384; i += 256) {
    float4 v = *(const float4*)(row + 1536 + i * 4);
    int hh = i >> 4;
    int p = (i & 15) << 2;
    ushort4 o;
    o.x = f2bf(v.x); o.y = f2bf(v.y); o.z = f2bf(v.z); o.w = f2bf(v.w);
    *(ushort4*)&Ub[((size_t)(hh * L_SEQ + l)) * HEADDIM + p] = o;
  }
  for (int i = tid; i < NHEADS * 96; i += 256) {
    int hh = i / 96, j = i - hh * 96;
    int n = 2 * j;
    float b0 = row[3072 + n], b1 = row[3072 + n + 1];
    float c0 = row[3264 + n], c1 = row[3264 + n + 1];
    size_t base = ((size_t)(hh * L_SEQ + l)) * DSTATE + n;
    float br0 = b0, br1 = b1, cr0 = c0, cr1 = c1;
    if (j < NPAIR) {
      float ph = cumdt[hh * L_SEQ + l] * omega[hh * NPAIR + j];
      float sp, cp;
      sincosf(ph, &sp, &cp);
      br0 =  b0 * cp + b1 * sp;
      br1 = -b0 * sp + b1 * cp;
      cr0 =  c0 * cp - c1 * sp;
      cr1 =  c0 * sp + c1 * cp;
    }
    ushort2 bo, co;
    bo.x = f2bf(br0); bo.y = f2bf(br1);
    co.x = f2bf(cr0); co.y = f2bf(cr1);
    *(ushort2*)&Brot[base] = bo;
    *(ushort2*)&Crot[base] = co;
  }
}

// ---------- K5: per-(head,chunk) state contribution X_c[p][n] ----------
__global__ __launch_bounds__(256) void k_chunkX(const unsigned short* __restrict__ Brot,
                                                const unsigned short* __restrict__ Ub,
                                                const float* __restrict__ cumD,
                                                const float* __restrict__ cfac,
                                                float* __restrict__ X) {
  const int c = blockIdx.x, hh = blockIdx.y;
  const int tid = threadIdx.x;
  const size_t hl = (size_t)hh * L_SEQ;
  const int l0 = c * QCH;
  __shared__ float Bs[QCH][DSTATE];
  __shared__ float su[QCH][HEADDIM];
  for (int i = tid; i < QCH * 48; i += 256) {
    int m = i / 48, q = i - m * 48;
    ushort4 bv = *(const ushort4*)&Brot[(hl + l0 + m) * DSTATE + (q << 2)];
    Bs[m][(q << 2) + 0] = bf2f(bv.x);
    Bs[m][(q << 2) + 1] = bf2f(bv.y);
    Bs[m][(q << 2) + 2] = bf2f(bv.z);
    Bs[m][(q << 2) + 3] = bf2f(bv.w);
  }
  float dlast = cumD[hl + l0 + QCH - 1];
  for (int i = tid; i < QCH * 16; i += 256) {
    int m = i >> 4, q = i & 15;
    float s = expf(dlast - cumD[hl + l0 + m]) * cfac[hl + l0 + m];
    ushort4 uv = *(const ushort4*)&Ub[(hl + l0 + m) * HEADDIM + (q << 2)];
    float4 v;
    v.x = bf2f(uv.x) * s; v.y = bf2f(uv.y) * s;
    v.z = bf2f(uv.z) * s; v.w = bf2f(uv.w) * s;
    *(float4*)&su[m][q << 2] = v;
  }
  __syncthreads();
  const int ngrp = tid & 15, pgrp = tid >> 4;
  const int n0 = ngrp * 12, p0 = pgrp << 2;
  float acc[12][4] = {};
  for (int m = 0; m < QCH; ++m) {
    const float4 uv = *(const float4*)&su[m][p0];
    const float4 b0 = *(const float4*)&Bs[m][n0];
    const float4 b1 = *(const float4*)&Bs[m][n0 + 4];
    const float4 b2 = *(const float4*)&Bs[m][n0 + 8];
    float u4[4] = {uv.x, uv.y, uv.z, uv.w};
    float bb[12] = {b0.x, b0.y, b0.z, b0.w, b1.x, b1.y, b1.z, b1.w, b2.x, b2.y, b2.z, b2.w};
#pragma unroll
    for (int j = 0; j < 12; ++j)
#pragma unroll
      for (int i = 0; i < 4; ++i) acc[j][i] = fmaf(bb[j], u4[i], acc[j][i]);
  }
  const size_t obase = ((size_t)(hh * NCHUNK + c)) * (HEADDIM * DSTATE);
#pragma unroll
  for (int i = 0; i < 4; ++i)
#pragma unroll
    for (int j4 = 0; j4 < 3; ++j4)
      *(float4*)&X[obase + (size_t)(p0 + i) * DSTATE + n0 + j4 * 4] =
          make_float4(acc[j4 * 4 + 0][i], acc[j4 * 4 + 1][i], acc[j4 * 4 + 2][i], acc[j4 * 4 + 3][i]);
}

// ---------- K6: sequential chunk-state pass (Hs bf16) ----------
__global__ __launch_bounds__(256) void k_statepass(const float* __restrict__ X,
                                                   const float* __restrict__ cumD,
                                                   unsigned short* __restrict__ Hs) {
  int hh = blockIdx.x >> 3, part = blockIdx.x & 7;
  int tid = threadIdx.x;
  const size_t hl = (size_t)hh * L_SEQ;
  float Hc[6] = {0.f, 0.f, 0.f, 0.f, 0.f, 0.f};
  for (int c = 0; c < NCHUNK; ++c) {
    float r = 1.f;
    if (c > 0) r = expf(cumD[hl + c * QCH + QCH - 1] - cumD[hl + c * QCH - 1]);
    size_t base = ((size_t)(hh * NCHUNK + c)) * (HEADDIM * DSTATE) + part * 1536 + tid;
#pragma unroll
    for (int k = 0; k < 6; ++k) {
      Hs[base + k * 256] = f2bf(Hc[k]);
      Hc[k] = fmaf(r, Hc[k], X[base + k * 256]);
    }
  }
}

// ---------- K7: per-(head,chunk) output Y via MFMA ----------
#define YP 104   // bf16 pad stride for 96-col K tiles
#define SP 72    // bf16 pad stride for 64-col tiles
__global__ __launch_bounds__(256) void k_yout_mfma(
    const unsigned short* __restrict__ Brot, const unsigned short* __restrict__ Crot,
    const unsigned short* __restrict__ Ub,   const unsigned short* __restrict__ Hs,
    const float* __restrict__ cumD, const float* __restrict__ cfac,
    const float* __restrict__ halfdt, const float* __restrict__ Dvec,
    float* __restrict__ Yout) {
  const int c = blockIdx.x, hh = blockIdx.y;
  const int tid = threadIdx.x;
  const int lane = tid & 63, w = tid >> 6;
  const int wr = w >> 1, wc = w & 1;
  const int r15 = lane & 15, kg = lane >> 4;
  const int l0 = c * QCH;
  const size_t hl = (size_t)hh * L_SEQ;

  __shared__ unsigned short Cs[64][YP];
  __shared__ unsigned short Bs[64][YP];   // reused for Hs tiles in Z phase
  __shared__ unsigned short Ss[64][SP];
  __shared__ unsigned short Ut[64][SP];
  __shared__ float Dc[64], cfs[64], hds[64];

  if (tid < 64) {
    Dc[tid]  = cumD[hl + l0 + tid];
    cfs[tid] = cfac[hl + l0 + tid];
    hds[tid] = halfdt[hl + l0 + tid];
  }
  // stage U transposed -> Ut[p][m] (raw ushort copy)
  for (int idx = tid; idx < 64 * 64; idx += 256) {
    int m = idx >> 6, p = idx & 63;
    Ut[p][m] = Ub[(hl + l0 + m) * HEADDIM + p];
  }

  // Phase A: S = C · B^T over K=192 in two halves of 96
  f32x4 accS[2][2] = {};
  for (int half = 0; half < 2; ++half) {
    __syncthreads();
    for (int idx = tid; idx < 64 * 12; idx += 256) {
      int t = idx / 12, q = (idx % 12) << 3;
      *(short8*)&Cs[t][q] = *(const short8*)&Crot[(hl + l0 + t) * DSTATE + 96 * half + q];
      *(short8*)&Bs[t][q] = *(const short8*)&Brot[(hl + l0 + t) * DSTATE + 96 * half + q];
    }
    __syncthreads();
#pragma unroll
    for (int kk = 0; kk < 3; ++kk) {
      short8 af[2], bfr[2];
#pragma unroll
      for (int i = 0; i < 2; ++i)
        af[i] = *(const short8*)&Cs[wr * 32 + i * 16 + r15][kk * 32 + kg * 8];
#pragma unroll
      for (int j = 0; j < 2; ++j)
        bfr[j] = *(const short8*)&Bs[wc * 32 + j * 16 + r15][kk * 32 + kg * 8];
#pragma unroll
      for (int i = 0; i < 2; ++i)
#pragma unroll
        for (int j = 0; j < 2; ++j)
          accS[i][j] = __builtin_amdgcn_mfma_f32_16x16x32_bf16(af[i], bfr[j], accS[i][j], 0, 0, 0);
    }
  }
  // apply causal trapezoid weights in fp32, write Sw to LDS as bf16
#pragma unroll
  for (int i = 0; i < 2; ++i)
#pragma unroll
    for (int j = 0; j < 2; ++j)
#pragma unroll
      for (int r = 0; r < 4; ++r) {
        int t = wr * 32 + i * 16 + kg * 4 + r;
        int m = wc * 32 + j * 16 + r15;
        float wgt = 0.f;
        if (m < t)       wgt = __expf(Dc[t] - Dc[m]) * cfs[m];
        else if (m == t) wgt = hds[t];
        Ss[t][m] = f2bf(accS[i][j][r] * wgt);
      }

  // Phase B: Z = C · Hs^T over K=192 in two halves
  f32x4 accZ[2][2] = {};
  const size_t hcb = ((size_t)(hh * NCHUNK + c)) * (HEADDIM * DSTATE);
  for (int half = 0; half < 2; ++half) {
    __syncthreads();
    for (int idx = tid; idx < 64 * 12; idx += 256) {
      int t = idx / 12, q = (idx % 12) << 3;
      *(short8*)&Cs[t][q] = *(const short8*)&Crot[(hl + l0 + t) * DSTATE + 96 * half + q];
      *(short8*)&Bs[t][q] = *(const short8*)&Hs[hcb + (size_t)t * DSTATE + 96 * half + q];
    }
    __syncthreads();
#pragma unroll
    for (int kk = 0; kk < 3; ++kk) {
      short8 af[2], bfr[2];
#pragma unroll
      for (int i = 0; i < 2; ++i)
        af[i] = *(const short8*)&Cs[wr * 32 + i * 16 + r15][kk * 32 + kg * 8];
#pragma unroll
      for (int j = 0; j < 2; ++j)
        bfr[j] = *(const short8*)&Bs[wc * 32 + j * 16 + r15][kk * 32 + kg * 8];
#pragma unroll
      for (int i = 0; i < 2; ++i)
#pragma unroll
        for (int j = 0; j < 2; ++j)
          accZ[i][j] = __builtin_amdgcn_mfma_f32_16x16x32_bf16(af[i], bfr[j], accZ[i][j], 0, 0, 0);
    }
  }

  // Phase C: Y1 = Sw · Ut^T (K = 64)
  f32x4 accY[2][2] = {};
#pragma unroll
  for (int kk = 0; kk < 2; ++kk) {
    short8 af[2], bfr[2];
#pragma unroll
    for (int i = 0; i < 2; ++i)
      af[i] = *(const short8*)&Ss[wr * 32 + i * 16 + r15][kk * 32 + kg * 8];
#pragma unroll
    for (int j = 0; j < 2; ++j)
      bfr[j] = *(const short8*)&Ut[wc * 32 + j * 16 + r15][kk * 32 + kg * 8];
#pragma unroll
    for (int i = 0; i < 2; ++i)
#pragma unroll
      for (int j = 0; j < 2; ++j)
        accY[i][j] = __builtin_amdgcn_mfma_f32_16x16x32_bf16(af[i], bfr[j], accY[i][j], 0, 0, 0);
  }

  // Epilogue
  float Dbase = (c > 0) ? cumD[hl + l0 - 1] : 0.f;
  float Dh = Dvec[hh];
#pragma unroll
  for (int i = 0; i < 2; ++i)
#pragma unroll
    for (int r = 0; r < 4; ++r) {
      int t = wr * 32 + i * 16 + kg * 4 + r;
      float et = __expf(Dc[t] - Dbase);
#pragma unroll
      for (int j = 0; j < 2; ++j) {
        int p = wc * 32 + j * 16 + r15;
        float u = bf2f(Ub[(hl + l0 + t) * HEADDIM + p]);
        Yout[(size_t)(l0 + t) * DINNER + hh * HEADDIM + p] =
            accY[i][j][r] + et * accZ[i][j][r] + Dh * u;
      }
    }
}

// ---------- K8: gate (silu) + RMSNorm over 1536 -> bf16 ----------
__global__ __launch_bounds__(256) void k_gate(const float* __restrict__ Y,
                                              const float* __restrict__ zx,
                                              const float* __restrict__ nw,
                                              unsigned short* __restrict__ Gh) {
  __shared__ float gbuf[DINNER];
  __shared__ float red[4];
  int l = blockIdx.x, tid = threadIdx.x;
  float ss = 0.f;
  for (int i = tid; i < DINNER; i += 256) {
    float y = Y[(size_t)l * DINNER + i];
    float z = zx[(size_t)l * DPROJ + i];
    float g = y * z / (1.f + expf(-z));
    gbuf[i] = g;
    ss += g * g;
  }
  ss = blockReduceSum256(ss, red);
  float r = rsqrtf(ss * (1.f / DINNER) + EPSF);
  for (int i = tid; i < DINNER; i += 256)
    Gh[(size_t)l * DINNER + i] = f2bf(gbuf[i] * r * nw[i]);
}

// ---------- K10: final RMSNorm + residual ----------
__global__ __launch_bounds__(256) void k_final(const float* __restrict__ x,
                                               const float* __restrict__ T,
                                               const float* __restrict__ post_scale,
                                               float* __restrict__ out) {
  __shared__ float red[4];
  int l = blockIdx.x, tid = threadIdx.x;
  const float* tr = T + (size_t)l * DMODEL;
  float v[3]; float ss = 0.f;
#pragma unroll
  for (int k = 0; k < 3; ++k) { v[k] = tr[tid + k * 256]; ss += v[k] * v[k]; }
  ss = blockReduceSum256(ss, red);
  float r = rsqrtf(ss * (1.f / DMODEL) + EPSF);
#pragma unroll
  for (int k = 0; k < 3; ++k) {
    int i = tid + k * 256;
    out[(size_t)l * DMODEL + i] = x[(size_t)l * DMODEL + i] + v[k] * r * (1.f + post_scale[i]);
  }
}

// ---------- launcher ----------
extern "C" void kernel_launch(void* const* d_in, const int* in_sizes, int n_in,
                              void* d_out, int out_size, void* d_ws, size_t ws_size,
                              hipStream_t stream) {
  const float* x      = (const float*)d_in[0];
  const float* pre_s  = (const float*)d_in[1];
  const float* W_in   = (const float*)d_in[2];
  const float* dt_b   = (const float*)d_in[3];
  const float* A_log  = (const float*)d_in[4];
  const float* omega  = (const float*)d_in[5];
  const float* Dvec   = (const float*)d_in[6];
  const float* nw     = (const float*)d_in[7];
  const float* W_out  = (const float*)d_in[8];
  const float* post_s = (const float*)d_in[9];
  float* out = (float*)d_out;

  float* ws = (float*)d_ws;
  size_t off = 0;
  auto nxt = [&](size_t n) { float* p = ws + off; off += (n + 3) & ~(size_t)3; return p; };
  float* ws_zx  = nxt((size_t)L_SEQ * DPROJ);
  unsigned short* ws_hb = (unsigned short*)nxt((size_t)L_SEQ * DMODEL / 2);
  float* ws_dtr = nxt((size_t)L_SEQ * NHEADS);
  float* ws_hd  = nxt((size_t)NHEADS * L_SEQ);
  float* ws_cf  = nxt((size_t)NHEADS * L_SEQ);
  float* ws_cdt = nxt((size_t)NHEADS * L_SEQ);
  float* ws_cD  = nxt((size_t)NHEADS * L_SEQ);
  unsigned short* ws_Brb = (unsigned short*)nxt((size_t)NHEADS * L_SEQ * DSTATE / 2);
  unsigned short* ws_Crb = (unsigned short*)nxt((size_t)NHEADS * L_SEQ * DSTATE / 2);
  unsigned short* ws_Ub  = (unsigned short*)nxt((size_t)NHEADS * L_SEQ * HEADDIM / 2);
  float* ws_X   = nxt((size_t)NHEADS * NCHUNK * HEADDIM * DSTATE);
  unsigned short* ws_Hsb = (unsigned short*)nxt((size_t)NHEADS * NCHUNK * HEADDIM * DSTATE / 2);
  float* ws_Y   = nxt((size_t)L_SEQ * DINNER);
  unsigned short* ws_Gh  = (unsigned short*)nxt((size_t)L_SEQ * DINNER / 2);
  unsigned short* ws_W1h = (unsigned short*)nxt((size_t)NPADJ * DMODEL / 2);   // dedicated
  unsigned short* ws_W2h = (unsigned short*)nxt((size_t)DMODEL * DINNER / 2);  // dedicated
  float* ws_T = ws_X;   // GEMM2 out; X dead after statepass

  k_cvtw2<<<112 * 24 + 24 * 48, 256, 0, stream>>>(W_in, ws_W1h, W_out, ws_W2h);
  k_prenorm_dt<<<L_SEQ, 256, 0, stream>>>(x, pre_s, W_in, ws_hb, ws_dtr);
  k_gemm_bf16<128, 64, 4, 2><<<dim3(NPADJ / 64, L_SEQ / 128), 256, 0, stream>>>(
      ws_hb, ws_W1h, ws_zx, DPROJ, DMODEL, DPROJ);
  k_dtscan<<<NHEADS, 256, 0, stream>>>(ws_dtr, dt_b, A_log, ws_hd, ws_cf, ws_cdt, ws_cD);
  k_rotate<<<L_SEQ, 256, 0, stream>>>(ws_zx, ws_cdt, omega, ws_Brb, ws_Crb, ws_Ub);
  k_chunkX<<<dim3(NCHUNK, NHEADS), 256, 0, stream>>>(ws_Brb, ws_Ub, ws_cD, ws_cf, ws_X);
  k_statepass<<<NHEADS * 8, 256, 0, stream>>>(ws_X, ws_cD, ws_Hsb);
  k_yout_mfma<<<dim3(NCHUNK, NHEADS), 256, 0, stream>>>(ws_Brb, ws_Crb, ws_Ub, ws_Hsb, ws_cD, ws_cf, ws_hd, Dvec, ws_Y);
  k_gate<<<L_SEQ, 256, 0, stream>>>(ws_Y, ws_zx, nw, ws_Gh);
  k_gemm_bf16<64, 64, 2, 2><<<dim3(DMODEL / 64, L_SEQ / 64), 256, 0, stream>>>(
      ws_Gh, ws_W2h, ws_T, DMODEL, DINNER, DMODEL);
  k_final<<<L_SEQ, 256, 0, stream>>>(x, ws_T, post_s, out);
}

// Round 11
// 189.436 us; speedup vs baseline: 1.9660x; 1.0507x over previous
//
#include <hip/hip_runtime.h>
#include <cstdint>

#define L_SEQ   1024
#define DMODEL  768
#define DINNER  1536
#define NHEADS  24
#define HEADDIM 64
#define DSTATE  192
#define NPAIR   48
#define DPROJ   3480
#define NPADJ   3584      // DPROJ padded to 128 multiple for GEMM1
#define NCHUNK  16
#define QCH     64
#define EPSF    1e-6f

typedef __attribute__((ext_vector_type(8))) short short8;
typedef __attribute__((ext_vector_type(4))) float f32x4;

__device__ __forceinline__ unsigned short f2bf(float x) {
  union { float f; uint32_t u; } v; v.f = x;
  uint32_t r = (v.u + 0x7FFFu + ((v.u >> 16) & 1u)) >> 16;
  return (unsigned short)r;
}
__device__ __forceinline__ float bf2f(unsigned short b) {
  union { float f; uint32_t u; } v; v.u = ((uint32_t)b) << 16;
  return v.f;
}

__device__ __forceinline__ float blockReduceSum256(float v, float* red) {
#pragma unroll
  for (int m = 32; m; m >>= 1) v += __shfl_xor(v, m, 64);
  int wid = threadIdx.x >> 6, lane = threadIdx.x & 63;
  if (lane == 0) red[wid] = v;
  __syncthreads();
  float s = red[0] + red[1] + red[2] + red[3];
  __syncthreads();
  return s;
}

// ---------- K0: weights fp32 [K][N] -> bf16 transposed [Npad][K]; + compact fp32 Wdt ----------
#define NB_W1 (112 * 24)
#define NB_W2 (24 * 48)
__global__ __launch_bounds__(256) void k_cvtw2(const float* __restrict__ Wa,
                                               unsigned short* __restrict__ Wha,
                                               const float* __restrict__ Wb,
                                               unsigned short* __restrict__ Whb,
                                               float* __restrict__ Wdt) {
  int b = blockIdx.x;
  if (b >= NB_W1 + NB_W2) {
    // compact dt columns: Wdt[k][c] = W_in[k*DPROJ + 3456 + c], k block of 32
    int kb = (b - NB_W1 - NB_W2) * 32;
    int k = threadIdx.x >> 3, cg = (threadIdx.x & 7) * 3;
    int kk = kb + k;
    const float* src = Wa + (size_t)kk * DPROJ + 3456 + cg;
    float* dst = Wdt + kk * 24 + cg;
    dst[0] = src[0]; dst[1] = src[1]; dst[2] = src[2];
    return;
  }
  __shared__ float tile[32][33];
  const float* W; unsigned short* Wt; int K, N, bx, by;
  if (b < NB_W1) {               // W_in: [768][3480] -> [3584][768]
    W = Wa; Wt = Wha; K = DMODEL; N = DPROJ; bx = b % 112; by = b / 112;
  } else {                       // W_out: [1536][768] -> [768][1536]
    b -= NB_W1;
    W = Wb; Wt = Whb; K = DINNER; N = DMODEL; bx = b % 24; by = b / 24;
  }
  int n0 = bx * 32, k0 = by * 32;
  int tr = threadIdx.x >> 3, tc4 = (threadIdx.x & 7) << 2;
  const float* wp = W + (size_t)(k0 + tr) * N + n0 + tc4;
  float4 v = make_float4(0.f, 0.f, 0.f, 0.f);
  if (n0 + tc4 + 3 < N) {
    v = *(const float4*)wp;
  } else {
    if (n0 + tc4     < N) v.x = wp[0];
    if (n0 + tc4 + 1 < N) v.y = wp[1];
    if (n0 + tc4 + 2 < N) v.z = wp[2];
    if (n0 + tc4 + 3 < N) v.w = wp[3];
  }
  tile[tr][tc4 + 0] = v.x; tile[tr][tc4 + 1] = v.y;
  tile[tr][tc4 + 2] = v.z; tile[tr][tc4 + 3] = v.w;
  __syncthreads();
  ushort4 oh;
  oh.x = f2bf(tile[tc4 + 0][tr]);
  oh.y = f2bf(tile[tc4 + 1][tr]);
  oh.z = f2bf(tile[tc4 + 2][tr]);
  oh.w = f2bf(tile[tc4 + 3][tr]);
  *(ushort4*)&Wt[(size_t)(n0 + tr) * K + k0 + tc4] = oh;
}

// ---------- K1: fused pre-RMSNorm + fp32 dt GEMV (coalesced Wdt) ----------
__global__ __launch_bounds__(256) void k_prenorm_dt(const float* __restrict__ x,
                                                    const float* __restrict__ pre_scale,
                                                    const float* __restrict__ Wdt,
                                                    unsigned short* __restrict__ hb,
                                                    float* __restrict__ dtr) {
  __shared__ float hs[DMODEL];
  __shared__ float red[4];
  __shared__ float part[8][NHEADS];
  int l = blockIdx.x, tid = threadIdx.x;
  const float* xr = x + (size_t)l * DMODEL;
  float v[3]; float ss = 0.f;
#pragma unroll
  for (int k = 0; k < 3; ++k) { v[k] = xr[tid + k * 256]; ss += v[k] * v[k]; }
  ss = blockReduceSum256(ss, red);
  float r = rsqrtf(ss * (1.f / DMODEL) + EPSF);
#pragma unroll
  for (int k = 0; k < 3; ++k) {
    int i = tid + k * 256;
    float hv = v[k] * r * (1.f + pre_scale[i]);
    hs[i] = hv;
    hb[(size_t)l * DMODEL + i] = f2bf(hv);
  }
  __syncthreads();
  if (tid < 192) {
    int hh = tid % 24, seg = tid / 24;   // consecutive threads -> consecutive hh (coalesced)
    float s = 0.f;
    int k0 = seg * 96;
#pragma unroll 4
    for (int k = k0; k < k0 + 96; ++k)
      s = fmaf(hs[k], Wdt[k * 24 + hh], s);
    part[seg][hh] = s;
  }
  __syncthreads();
  if (tid < NHEADS) {
    float s = 0.f;
#pragma unroll
    for (int q = 0; q < 8; ++q) s += part[q][tid];
    dtr[(size_t)l * NHEADS + tid] = s;
  }
}

// ---------- K2/K9: bf16 MFMA GEMM, reg-staged double buffer, small tiles ----------
template<int BM, int BN, int TM, int TN>
__global__ __launch_bounds__(256) void k_gemm_bf16(
    const unsigned short* __restrict__ A,
    const unsigned short* __restrict__ Bt,
    float* __restrict__ C,
    int N, int K, int ldc) {
  constexpr int ACH = BM * 4;   // short8 chunks for A tile (32-K wide)
  constexpr int BCH = BN * 4;
  __shared__ unsigned short As[BM * 32];
  __shared__ unsigned short Bs[BN * 32];
  const int tid = threadIdx.x;
  const int lane = tid & 63, w = tid >> 6;
  const int wm = (w >> 1) * (TM * 16), wn = (w & 1) * (TN * 16);
  const int bm = blockIdx.y * BM, bn = blockIdx.x * BN;
  const int r15 = lane & 15, kg = lane >> 4;
  f32x4 acc[TM][TN] = {};
  if constexpr (ACH % 256 == 0 && BCH % 256 == 0) {
    constexpr int AC = ACH / 256, BC = BCH / 256;
    short8 ra[AC], rb[BC];
    auto loadG = [&](int k0) {
#pragma unroll
      for (int a = 0; a < AC; ++a) {
        int idx = tid + a * 256; int r = idx >> 2, kq = (idx & 3) << 3;
        ra[a] = *(const short8*)&A[(size_t)(bm + r) * K + k0 + kq];
      }
#pragma unroll
      for (int b = 0; b < BC; ++b) {
        int idx = tid + b * 256; int r = idx >> 2, kq = (idx & 3) << 3;
        rb[b] = *(const short8*)&Bt[(size_t)(bn + r) * K + k0 + kq];
      }
    };
    loadG(0);
    for (int k0 = 0; k0 < K; k0 += 32) {
#pragma unroll
      for (int a = 0; a < AC; ++a) {
        int idx = tid + a * 256; int r = idx >> 2, kq = (idx & 3) << 3;
        *(short8*)&As[r * 32 + kq] = ra[a];
      }
#pragma unroll
      for (int b = 0; b < BC; ++b) {
        int idx = tid + b * 256; int r = idx >> 2, kq = (idx & 3) << 3;
        *(short8*)&Bs[r * 32 + kq] = rb[b];
      }
      __syncthreads();
      if (k0 + 32 < K) loadG(k0 + 32);
      short8 af[TM], bfr[TN];
#pragma unroll
      for (int i = 0; i < TM; ++i)
        af[i] = *(const short8*)&As[(wm + i * 16 + r15) * 32 + kg * 8];
#pragma unroll
      for (int j = 0; j < TN; ++j)
        bfr[j] = *(const short8*)&Bs[(wn + j * 16 + r15) * 32 + kg * 8];
#pragma unroll
      for (int i = 0; i < TM; ++i)
#pragma unroll
        for (int j = 0; j < TN; ++j)
          acc[i][j] = __builtin_amdgcn_mfma_f32_16x16x32_bf16(af[i], bfr[j], acc[i][j], 0, 0, 0);
      __syncthreads();
    }
  } else {
    // combined path: ACH + BCH <= 256, one chunk per thread
    static_assert(ACH + BCH <= 256, "tile too small/large for combined staging");
    short8 rc;
    const bool isA = tid < ACH;
    const bool act = tid < ACH + BCH;
    int ci = isA ? tid : tid - ACH;
    int cr = ci >> 2, ckq = (ci & 3) << 3;
    auto loadG = [&](int k0) {
      if (act) {
        if (isA) rc = *(const short8*)&A[(size_t)(bm + cr) * K + k0 + ckq];
        else     rc = *(const short8*)&Bt[(size_t)(bn + cr) * K + k0 + ckq];
      }
    };
    loadG(0);
    for (int k0 = 0; k0 < K; k0 += 32) {
      if (act) {
        if (isA) *(short8*)&As[cr * 32 + ckq] = rc;
        else     *(short8*)&Bs[cr * 32 + ckq] = rc;
      }
      __syncthreads();
      if (k0 + 32 < K) loadG(k0 + 32);
      short8 af[TM], bfr[TN];
#pragma unroll
      for (int i = 0; i < TM; ++i)
        af[i] = *(const short8*)&As[(wm + i * 16 + r15) * 32 + kg * 8];
#pragma unroll
      for (int j = 0; j < TN; ++j)
        bfr[j] = *(const short8*)&Bs[(wn + j * 16 + r15) * 32 + kg * 8];
#pragma unroll
      for (int i = 0; i < TM; ++i)
#pragma unroll
        for (int j = 0; j < TN; ++j)
          acc[i][j] = __builtin_amdgcn_mfma_f32_16x16x32_bf16(af[i], bfr[j], acc[i][j], 0, 0, 0);
      __syncthreads();
    }
  }
  const int crow = bm + wm + (lane >> 4) * 4;
  const int ccol = bn + wn + r15;
#pragma unroll
  for (int i = 0; i < TM; ++i)
#pragma unroll
    for (int j = 0; j < TN; ++j) {
      int col = ccol + j * 16;
      if (col < N) {
        float* cp = C + (size_t)(crow + i * 16) * ldc + col;
#pragma unroll
        for (int r = 0; r < 4; ++r) cp[(size_t)r * ldc] = acc[i][j][r];
      }
    }
}

// ---------- K3: dt softplus + cumsum, shuffle scan ----------
__global__ __launch_bounds__(256) void k_dtscan(const float* __restrict__ dtr,
                                                const float* __restrict__ dt_bias,
                                                const float* __restrict__ A_log,
                                                float* __restrict__ halfdt,
                                                float* __restrict__ cfac,
                                                float* __restrict__ cumdt,
                                                float* __restrict__ cumD) {
  __shared__ float sdt[L_SEQ];
  __shared__ float wsum[4];
  int hh = blockIdx.x, tid = threadIdx.x;
  int lane = tid & 63, wid = tid >> 6;
  float bias = dt_bias[hh];
  float Ah = -(expf(A_log[hh]) + 1e-4f);
  int l0 = tid * 4;
  float d[4], e[4];
#pragma unroll
  for (int k = 0; k < 4; ++k) {
    float draw = dtr[(size_t)(l0 + k) * NHEADS + hh] + bias;
    d[k] = (draw > 20.f) ? draw : log1pf(expf(draw));
    sdt[l0 + k] = d[k];
  }
  e[0] = d[0]; e[1] = e[0] + d[1]; e[2] = e[1] + d[2]; e[3] = e[2] + d[3];
  float tot = e[3];
  float s = tot;
#pragma unroll
  for (int off = 1; off < 64; off <<= 1) {
    float n = __shfl_up(s, off, 64);
    if (lane >= off) s += n;
  }
  if (lane == 63) wsum[wid] = s;
  __syncthreads();
  float woff = 0.f;
#pragma unroll
  for (int q = 0; q < 4; ++q) woff += (q < wid) ? wsum[q] : 0.f;
  float excl = woff + s - tot;
  float cd0 = excl + e[0], cd1 = excl + e[1], cd2 = excl + e[2], cd3 = excl + e[3];
  float dnext3 = (l0 + 3 < L_SEQ - 1) ? sdt[l0 + 4] : 0.f;
  float4 o_hd = make_float4(0.5f * d[0], 0.5f * d[1], 0.5f * d[2], 0.5f * d[3]);
  float4 o_cf = make_float4(0.5f * (d[0] + d[1]), 0.5f * (d[1] + d[2]),
                            0.5f * (d[2] + d[3]), 0.5f * (d[3] + dnext3));
  float4 o_cd = make_float4(cd0, cd1, cd2, cd3);
  float4 o_cD = make_float4(Ah * cd0, Ah * cd1, Ah * cd2, Ah * cd3);
  size_t idx = (size_t)hh * L_SEQ + l0;
  *(float4*)&halfdt[idx] = o_hd;
  *(float4*)&cfac[idx]   = o_cf;
  *(float4*)&cumdt[idx]  = o_cd;
  *(float4*)&cumD[idx]   = o_cD;
}

// ---------- K4: rotate B/C per head (bf16) + gather U contiguous (bf16) ----------
__global__ __launch_bounds__(256) void k_rotate(const float* __restrict__ zx,
                                                const float* __restrict__ cumdt,
                                                const float* __restrict__ omega,
                                                unsigned short* __restrict__ Brot,
                                                unsigned short* __restrict__ Crot,
                                                unsigned short* __restrict__ Ub) {
  int l = blockIdx.x, tid = threadIdx.x;
  const float* row = zx + (size_t)l * DPROJ;
  for (int i = tid; i < 384; i += 256) {
    float4 v = *(const float4*)(row + 1536 + i * 4);
    int hh = i >> 4;
    int p = (i & 15) << 2;
    ushort4 o;
    o.x = f2bf(v.x); o.y = f2bf(v.y); o.z = f2bf(v.z); o.w = f2bf(v.w);
    *(ushort4*)&Ub[((size_t)(hh * L_SEQ + l)) * HEADDIM + p] = o;
  }
  for (int i = tid; i < NHEADS * 96; i += 256) {
    int hh = i / 96, j = i - hh * 96;
    int n = 2 * j;
    float b0 = row[3072 + n], b1 = row[3072 + n + 1];
    float c0 = row[3264 + n], c1 = row[3264 + n + 1];
    size_t base = ((size_t)(hh * L_SEQ + l)) * DSTATE + n;
    float br0 = b0, br1 = b1, cr0 = c0, cr1 = c1;
    if (j < NPAIR) {
      float ph = cumdt[hh * L_SEQ + l] * omega[hh * NPAIR + j];
      float sp, cp;
      sincosf(ph, &sp, &cp);
      br0 =  b0 * cp + b1 * sp;
      br1 = -b0 * sp + b1 * cp;
      cr0 =  c0 * cp - c1 * sp;
      cr1 =  c0 * sp + c1 * cp;
    }
    ushort2 bo, co;
    bo.x = f2bf(br0); bo.y = f2bf(br1);
    co.x = f2bf(cr0); co.y = f2bf(cr1);
    *(ushort2*)&Brot[base] = bo;
    *(ushort2*)&Crot[base] = co;
  }
}

// ---------- K5: per-(head,chunk) state contribution X_c[p][n] ----------
__global__ __launch_bounds__(256) void k_chunkX(const unsigned short* __restrict__ Brot,
                                                const unsigned short* __restrict__ Ub,
                                                const float* __restrict__ cumD,
                                                const float* __restrict__ cfac,
                                                float* __restrict__ X) {
  const int c = blockIdx.x, hh = blockIdx.y;
  const int tid = threadIdx.x;
  const size_t hl = (size_t)hh * L_SEQ;
  const int l0 = c * QCH;
  __shared__ float Bs[QCH][DSTATE];
  __shared__ float su[QCH][HEADDIM];
  for (int i = tid; i < QCH * 48; i += 256) {
    int m = i / 48, q = i - m * 48;
    ushort4 bv = *(const ushort4*)&Brot[(hl + l0 + m) * DSTATE + (q << 2)];
    Bs[m][(q << 2) + 0] = bf2f(bv.x);
    Bs[m][(q << 2) + 1] = bf2f(bv.y);
    Bs[m][(q << 2) + 2] = bf2f(bv.z);
    Bs[m][(q << 2) + 3] = bf2f(bv.w);
  }
  float dlast = cumD[hl + l0 + QCH - 1];
  for (int i = tid; i < QCH * 16; i += 256) {
    int m = i >> 4, q = i & 15;
    float s = expf(dlast - cumD[hl + l0 + m]) * cfac[hl + l0 + m];
    ushort4 uv = *(const ushort4*)&Ub[(hl + l0 + m) * HEADDIM + (q << 2)];
    float4 v;
    v.x = bf2f(uv.x) * s; v.y = bf2f(uv.y) * s;
    v.z = bf2f(uv.z) * s; v.w = bf2f(uv.w) * s;
    *(float4*)&su[m][q << 2] = v;
  }
  __syncthreads();
  const int ngrp = tid & 15, pgrp = tid >> 4;
  const int n0 = ngrp * 12, p0 = pgrp << 2;
  float acc[12][4] = {};
  for (int m = 0; m < QCH; ++m) {
    const float4 uv = *(const float4*)&su[m][p0];
    const float4 b0 = *(const float4*)&Bs[m][n0];
    const float4 b1 = *(const float4*)&Bs[m][n0 + 4];
    const float4 b2 = *(const float4*)&Bs[m][n0 + 8];
    float u4[4] = {uv.x, uv.y, uv.z, uv.w};
    float bb[12] = {b0.x, b0.y, b0.z, b0.w, b1.x, b1.y, b1.z, b1.w, b2.x, b2.y, b2.z, b2.w};
#pragma unroll
    for (int j = 0; j < 12; ++j)
#pragma unroll
      for (int i = 0; i < 4; ++i) acc[j][i] = fmaf(bb[j], u4[i], acc[j][i]);
  }
  const size_t obase = ((size_t)(hh * NCHUNK + c)) * (HEADDIM * DSTATE);
#pragma unroll
  for (int i = 0; i < 4; ++i)
#pragma unroll
    for (int j4 = 0; j4 < 3; ++j4)
      *(float4*)&X[obase + (size_t)(p0 + i) * DSTATE + n0 + j4 * 4] =
          make_float4(acc[j4 * 4 + 0][i], acc[j4 * 4 + 1][i], acc[j4 * 4 + 2][i], acc[j4 * 4 + 3][i]);
}

// ---------- K6: sequential chunk-state pass (Hs bf16, float2 I/O) ----------
__global__ __launch_bounds__(256) void k_statepass(const float* __restrict__ X,
                                                   const float* __restrict__ cumD,
                                                   unsigned short* __restrict__ Hs) {
  int hh = blockIdx.x >> 3, part = blockIdx.x & 7;
  int tid = threadIdx.x;
  const size_t hl = (size_t)hh * L_SEQ;
  float2 Hc[3];
#pragma unroll
  for (int k = 0; k < 3; ++k) Hc[k] = make_float2(0.f, 0.f);
  for (int c = 0; c < NCHUNK; ++c) {
    float r = 1.f;
    if (c > 0) r = expf(cumD[hl + c * QCH + QCH - 1] - cumD[hl + c * QCH - 1]);
    size_t base2 = (((size_t)(hh * NCHUNK + c)) * (HEADDIM * DSTATE) + part * 1536) / 2 + tid;
#pragma unroll
    for (int k = 0; k < 3; ++k) {
      size_t i2 = base2 + k * 256;
      ushort2 ho;
      ho.x = f2bf(Hc[k].x); ho.y = f2bf(Hc[k].y);
      *(ushort2*)&Hs[i2 * 2] = ho;
      float2 xv = *(const float2*)&X[i2 * 2];
      Hc[k].x = fmaf(r, Hc[k].x, xv.x);
      Hc[k].y = fmaf(r, Hc[k].y, xv.y);
    }
  }
}

// ---------- K7: per-(head,chunk) output Y via MFMA ----------
#define YP 104   // bf16 pad stride for 96-col K tiles
#define SP 72    // bf16 pad stride for 64-col tiles
__global__ __launch_bounds__(256) void k_yout_mfma(
    const unsigned short* __restrict__ Brot, const unsigned short* __restrict__ Crot,
    const unsigned short* __restrict__ Ub,   const unsigned short* __restrict__ Hs,
    const float* __restrict__ cumD, const float* __restrict__ cfac,
    const float* __restrict__ halfdt, const float* __restrict__ Dvec,
    float* __restrict__ Yout) {
  const int c = blockIdx.x, hh = blockIdx.y;
  const int tid = threadIdx.x;
  const int lane = tid & 63, w = tid >> 6;
  const int wr = w >> 1, wc = w & 1;
  const int r15 = lane & 15, kg = lane >> 4;
  const int l0 = c * QCH;
  const size_t hl = (size_t)hh * L_SEQ;

  __shared__ unsigned short Cs[64][YP];
  __shared__ unsigned short Bs[64][YP];   // reused for Hs tiles in Z phase
  __shared__ unsigned short Ss[64][SP];
  __shared__ unsigned short Ut[64][SP];
  __shared__ float Dc[64], cfs[64], hds[64];

  if (tid < 64) {
    Dc[tid]  = cumD[hl + l0 + tid];
    cfs[tid] = cfac[hl + l0 + tid];
    hds[tid] = halfdt[hl + l0 + tid];
  }
  // stage U transposed -> Ut[p][m]
  for (int idx = tid; idx < 64 * 64; idx += 256) {
    int m = idx >> 6, p = idx & 63;
    Ut[p][m] = Ub[(hl + l0 + m) * HEADDIM + p];
  }

  // Phase A: S = C · B^T over K=192 in two halves of 96
  f32x4 accS[2][2] = {};
  for (int half = 0; half < 2; ++half) {
    __syncthreads();
    for (int idx = tid; idx < 64 * 12; idx += 256) {
      int t = idx / 12, q = (idx % 12) << 3;
      *(short8*)&Cs[t][q] = *(const short8*)&Crot[(hl + l0 + t) * DSTATE + 96 * half + q];
      *(short8*)&Bs[t][q] = *(const short8*)&Brot[(hl + l0 + t) * DSTATE + 96 * half + q];
    }
    __syncthreads();
#pragma unroll
    for (int kk = 0; kk < 3; ++kk) {
      short8 af[2], bfr[2];
#pragma unroll
      for (int i = 0; i < 2; ++i)
        af[i] = *(const short8*)&Cs[wr * 32 + i * 16 + r15][kk * 32 + kg * 8];
#pragma unroll
      for (int j = 0; j < 2; ++j)
        bfr[j] = *(const short8*)&Bs[wc * 32 + j * 16 + r15][kk * 32 + kg * 8];
#pragma unroll
      for (int i = 0; i < 2; ++i)
#pragma unroll
        for (int j = 0; j < 2; ++j)
          accS[i][j] = __builtin_amdgcn_mfma_f32_16x16x32_bf16(af[i], bfr[j], accS[i][j], 0, 0, 0);
    }
  }
  // apply causal trapezoid weights in fp32, write Sw to LDS as bf16
#pragma unroll
  for (int i = 0; i < 2; ++i)
#pragma unroll
    for (int j = 0; j < 2; ++j)
#pragma unroll
      for (int r = 0; r < 4; ++r) {
        int t = wr * 32 + i * 16 + kg * 4 + r;
        int m = wc * 32 + j * 16 + r15;
        float wgt = 0.f;
        if (m < t)       wgt = __expf(Dc[t] - Dc[m]) * cfs[m];
        else if (m == t) wgt = hds[t];
        Ss[t][m] = f2bf(accS[i][j][r] * wgt);
      }

  // Phase B: Z = C · Hs^T over K=192 in two halves
  f32x4 accZ[2][2] = {};
  const size_t hcb = ((size_t)(hh * NCHUNK + c)) * (HEADDIM * DSTATE);
  for (int half = 0; half < 2; ++half) {
    __syncthreads();
    for (int idx = tid; idx < 64 * 12; idx += 256) {
      int t = idx / 12, q = (idx % 12) << 3;
      *(short8*)&Cs[t][q] = *(const short8*)&Crot[(hl + l0 + t) * DSTATE + 96 * half + q];
      *(short8*)&Bs[t][q] = *(const short8*)&Hs[hcb + (size_t)t * DSTATE + 96 * half + q];
    }
    __syncthreads();
#pragma unroll
    for (int kk = 0; kk < 3; ++kk) {
      short8 af[2], bfr[2];
#pragma unroll
      for (int i = 0; i < 2; ++i)
        af[i] = *(const short8*)&Cs[wr * 32 + i * 16 + r15][kk * 32 + kg * 8];
#pragma unroll
      for (int j = 0; j < 2; ++j)
        bfr[j] = *(const short8*)&Bs[wc * 32 + j * 16 + r15][kk * 32 + kg * 8];
#pragma unroll
      for (int i = 0; i < 2; ++i)
#pragma unroll
        for (int j = 0; j < 2; ++j)
          accZ[i][j] = __builtin_amdgcn_mfma_f32_16x16x32_bf16(af[i], bfr[j], accZ[i][j], 0, 0, 0);
    }
  }

  // Phase C: Y1 = Sw · Ut^T (K = 64)
  f32x4 accY[2][2] = {};
#pragma unroll
  for (int kk = 0; kk < 2; ++kk) {
    short8 af[2], bfr[2];
#pragma unroll
    for (int i = 0; i < 2; ++i)
      af[i] = *(const short8*)&Ss[wr * 32 + i * 16 + r15][kk * 32 + kg * 8];
#pragma unroll
    for (int j = 0; j < 2; ++j)
      bfr[j] = *(const short8*)&Ut[wc * 32 + j * 16 + r15][kk * 32 + kg * 8];
#pragma unroll
    for (int i = 0; i < 2; ++i)
#pragma unroll
      for (int j = 0; j < 2; ++j)
        accY[i][j] = __builtin_amdgcn_mfma_f32_16x16x32_bf16(af[i], bfr[j], accY[i][j], 0, 0, 0);
  }

  // Epilogue
  float Dbase = (c > 0) ? cumD[hl + l0 - 1] : 0.f;
  float Dh = Dvec[hh];
#pragma unroll
  for (int i = 0; i < 2; ++i)
#pragma unroll
    for (int r = 0; r < 4; ++r) {
      int t = wr * 32 + i * 16 + kg * 4 + r;
      float et = __expf(Dc[t] - Dbase);
#pragma unroll
      for (int j = 0; j < 2; ++j) {
        int p = wc * 32 + j * 16 + r15;
        float u = bf2f(Ub[(hl + l0 + t) * HEADDIM + p]);
        Yout[(size_t)(l0 + t) * DINNER + hh * HEADDIM + p] =
            accY[i][j][r] + et * accZ[i][j][r] + Dh * u;
      }
    }
}

// ---------- K8: gate (silu) + RMSNorm over 1536 -> bf16 ----------
__global__ __launch_bounds__(256) void k_gate(const float* __restrict__ Y,
                                              const float* __restrict__ zx,
                                              const float* __restrict__ nw,
                                              unsigned short* __restrict__ Gh) {
  __shared__ float gbuf[DINNER];
  __shared__ float red[4];
  int l = blockIdx.x, tid = threadIdx.x;
  float ss = 0.f;
  for (int i = tid; i < DINNER; i += 256) {
    float y = Y[(size_t)l * DINNER + i];
    float z = zx[(size_t)l * DPROJ + i];
    float g = y * z / (1.f + expf(-z));
    gbuf[i] = g;
    ss += g * g;
  }
  ss = blockReduceSum256(ss, red);
  float r = rsqrtf(ss * (1.f / DINNER) + EPSF);
  for (int i = tid; i < DINNER; i += 256)
    Gh[(size_t)l * DINNER + i] = f2bf(gbuf[i] * r * nw[i]);
}

// ---------- K10: final RMSNorm + residual ----------
__global__ __launch_bounds__(256) void k_final(const float* __restrict__ x,
                                               const float* __restrict__ T,
                                               const float* __restrict__ post_scale,
                                               float* __restrict__ out) {
  __shared__ float red[4];
  int l = blockIdx.x, tid = threadIdx.x;
  const float* tr = T + (size_t)l * DMODEL;
  float v[3]; float ss = 0.f;
#pragma unroll
  for (int k = 0; k < 3; ++k) { v[k] = tr[tid + k * 256]; ss += v[k] * v[k]; }
  ss = blockReduceSum256(ss, red);
  float r = rsqrtf(ss * (1.f / DMODEL) + EPSF);
#pragma unroll
  for (int k = 0; k < 3; ++k) {
    int i = tid + k * 256;
    out[(size_t)l * DMODEL + i] = x[(size_t)l * DMODEL + i] + v[k] * r * (1.f + post_scale[i]);
  }
}

// ---------- launcher ----------
extern "C" void kernel_launch(void* const* d_in, const int* in_sizes, int n_in,
                              void* d_out, int out_size, void* d_ws, size_t ws_size,
                              hipStream_t stream) {
  const float* x      = (const float*)d_in[0];
  const float* pre_s  = (const float*)d_in[1];
  const float* W_in   = (const float*)d_in[2];
  const float* dt_b   = (const float*)d_in[3];
  const float* A_log  = (const float*)d_in[4];
  const float* omega  = (const float*)d_in[5];
  const float* Dvec   = (const float*)d_in[6];
  const float* nw     = (const float*)d_in[7];
  const float* W_out  = (const float*)d_in[8];
  const float* post_s = (const float*)d_in[9];
  float* out = (float*)d_out;

  float* ws = (float*)d_ws;
  size_t off = 0;
  auto nxt = [&](size_t n) { float* p = ws + off; off += (n + 3) & ~(size_t)3; return p; };
  float* ws_zx  = nxt((size_t)L_SEQ * DPROJ);
  unsigned short* ws_hb = (unsigned short*)nxt((size_t)L_SEQ * DMODEL / 2);
  float* ws_dtr = nxt((size_t)L_SEQ * NHEADS);
  float* ws_hd  = nxt((size_t)NHEADS * L_SEQ);
  float* ws_cf  = nxt((size_t)NHEADS * L_SEQ);
  float* ws_cdt = nxt((size_t)NHEADS * L_SEQ);
  float* ws_cD  = nxt((size_t)NHEADS * L_SEQ);
  unsigned short* ws_Brb = (unsigned short*)nxt((size_t)NHEADS * L_SEQ * DSTATE / 2);
  unsigned short* ws_Crb = (unsigned short*)nxt((size_t)NHEADS * L_SEQ * DSTATE / 2);
  unsigned short* ws_Ub  = (unsigned short*)nxt((size_t)NHEADS * L_SEQ * HEADDIM / 2);
  float* ws_X   = nxt((size_t)NHEADS * NCHUNK * HEADDIM * DSTATE);
  unsigned short* ws_Hsb = (unsigned short*)nxt((size_t)NHEADS * NCHUNK * HEADDIM * DSTATE / 2);
  float* ws_Y   = nxt((size_t)L_SEQ * DINNER);
  unsigned short* ws_Gh  = (unsigned short*)nxt((size_t)L_SEQ * DINNER / 2);
  unsigned short* ws_W1h = (unsigned short*)nxt((size_t)NPADJ * DMODEL / 2);
  unsigned short* ws_W2h = (unsigned short*)nxt((size_t)DMODEL * DINNER / 2);
  float* ws_Wdt = nxt((size_t)DMODEL * NHEADS);
  float* ws_T = ws_X;   // GEMM2 out; X dead after statepass

  k_cvtw2<<<NB_W1 + NB_W2 + 24, 256, 0, stream>>>(W_in, ws_W1h, W_out, ws_W2h, ws_Wdt);
  k_prenorm_dt<<<L_SEQ, 256, 0, stream>>>(x, pre_s, ws_Wdt, ws_hb, ws_dtr);
  k_gemm_bf16<64, 64, 2, 2><<<dim3(NPADJ / 64, L_SEQ / 64), 256, 0, stream>>>(
      ws_hb, ws_W1h, ws_zx, DPROJ, DMODEL, DPROJ);
  k_dtscan<<<NHEADS, 256, 0, stream>>>(ws_dtr, dt_b, A_log, ws_hd, ws_cf, ws_cdt, ws_cD);
  k_rotate<<<L_SEQ, 256, 0, stream>>>(ws_zx, ws_cdt, omega, ws_Brb, ws_Crb, ws_Ub);
  k_chunkX<<<dim3(NCHUNK, NHEADS), 256, 0, stream>>>(ws_Brb, ws_Ub, ws_cD, ws_cf, ws_X);
  k_statepass<<<NHEADS * 8, 256, 0, stream>>>(ws_X, ws_cD, ws_Hsb);
  k_yout_mfma<<<dim3(NCHUNK, NHEADS), 256, 0, stream>>>(ws_Brb, ws_Crb, ws_Ub, ws_Hsb, ws_cD, ws_cf, ws_hd, Dvec, ws_Y);
  k_gate<<<L_SEQ, 256, 0, stream>>>(ws_Y, ws_zx, nw, ws_Gh);
  k_gemm_bf16<32, 32, 1, 1><<<dim3(DMODEL / 32, L_SEQ / 32), 256, 0, stream>>>(
      ws_Gh, ws_W2h, ws_T, DMODEL, DINNER, DMODEL);
  k_final<<<L_SEQ, 256, 0, stream>>>(x, ws_T, post_s, out);
}